// Round 3
// baseline (945.009 us; speedup 1.0000x reference)
//
#include <hip/hip_runtime.h>
#include <hip/hip_bf16.h>
#include <stdint.h>

typedef __attribute__((ext_vector_type(4))) float f4;
typedef __attribute__((ext_vector_type(2))) float f2;
typedef __attribute__((ext_vector_type(8))) unsigned short us8;
typedef __attribute__((ext_vector_type(4))) unsigned short us4;
typedef __attribute__((ext_vector_type(2))) unsigned short us2;

__device__ __forceinline__ float bf2f(unsigned short u) {
  union { unsigned int i; float f; } t; t.i = ((unsigned int)u) << 16; return t.f;
}
__device__ __forceinline__ unsigned short f2bf(float f) {
  union { float f; unsigned int i; } t; t.f = f;
  unsigned int u = t.i;
  return (unsigned short)((u + 0x7FFFu + ((u >> 16) & 1u)) >> 16);
}

// ---- dtype detection (device float arrays may be fp32 or bf16; indices int32/int64) ----
__global__ void detect_kernel(const unsigned int* __restrict__ xb,
                              const unsigned int* __restrict__ ib,
                              int* __restrict__ flags) {
  if (threadIdx.x == 0) {
    int cnt = 0;
    for (int i = 0; i < 256; ++i) {
      unsigned int e = (xb[i] >> 7) & 0xffu;   // low-bf16 exponent field if packed bf16
      if (e >= 110u && e <= 135u) ++cnt;
    }
    flags[0] = (cnt >= 180) ? 1 : 0;           // fp32 mantissa bits -> cnt ~26
    int zc = 0;
    for (int i = 0; i < 128; ++i) if (ib[2 * i + 1] == 0u) ++zc;  // int64 high words
    flags[1] = (zc >= 120) ? 1 : 0;
  }
}

__global__ void cvt_f32(const void* __restrict__ src, float* __restrict__ dst,
                        int n, const int* __restrict__ flags) {
  int i = blockIdx.x * 256 + threadIdx.x;
  if (i >= n) return;
  if (flags[0]) dst[i] = bf2f(((const unsigned short*)src)[i]);
  else          dst[i] = ((const float*)src)[i];
}

__global__ void cvt_idx(const void* __restrict__ src, int* __restrict__ dst,
                        int n, const int* __restrict__ flags) {
  int i = blockIdx.x * 256 + threadIdx.x;
  if (i >= n) return;
  if (flags[1]) dst[i] = (int)(((const long long*)src)[i]);
  else          dst[i] = ((const int*)src)[i];
}

// ---- degrees ----
__global__ void deg_kernel(const int* __restrict__ row, const int* __restrict__ col,
                           const float* __restrict__ wM, const float* __restrict__ ew,
                           float* __restrict__ nd, float* __restrict__ hd, int M) {
  int m = blockIdx.x * 256 + threadIdx.x;
  if (m >= M) return;
  int r = row[m], c = col[m];
  atomicAdd(nd + r, wM[c]);
  atomicAdd(hd + c, ew[m]);
}

__global__ void finish_deg_kernel(float* __restrict__ nd, float* __restrict__ hd,
                                  int N, int E) {
  int i = blockIdx.x * 256 + threadIdx.x;
  if (i < N) nd[i] = rsqrtf(nd[i] + 1e-8f);
  if (i < E) hd[i] = rsqrtf(hd[i] + 1e-8f);
}

// ---- CSR build ----
__global__ void hist_kernel(const int* __restrict__ row, const int* __restrict__ col,
                            int* __restrict__ cntE, int* __restrict__ cntN, int M) {
  int m = blockIdx.x * 256 + threadIdx.x;
  if (m >= M) return;
  atomicAdd(cntE + col[m], 1);
  atomicAdd(cntN + row[m], 1);
}

// single-block exclusive scan, chunked Hillis-Steele
__global__ __launch_bounds__(1024) void scan_kernel(const int* __restrict__ cnt,
                                                    int* __restrict__ off, int n) {
  __shared__ int buf[1024];
  __shared__ int base_s;
  int tid = threadIdx.x;
  if (tid == 0) base_s = 0;
  __syncthreads();
  for (int c0 = 0; c0 < n; c0 += 1024) {
    int i = c0 + tid;
    int v = (i < n) ? cnt[i] : 0;
    buf[tid] = v;
    __syncthreads();
    for (int s = 1; s < 1024; s <<= 1) {
      int t = (tid >= s) ? buf[tid - s] : 0;
      __syncthreads();
      buf[tid] += t;
      __syncthreads();
    }
    if (i < n) off[i] = base_s + buf[tid] - v;
    __syncthreads();
    if (tid == 0) base_s += buf[1023];
    __syncthreads();
  }
  if (tid == 0) off[n] = base_s;
}

__global__ void permfill_kernel(const int* __restrict__ ROW, const int* __restrict__ COL,
                                const float* __restrict__ WMf, const float* __restrict__ EWf,
                                const float* __restrict__ ND, const float* __restrict__ HD,
                                const int* __restrict__ offE, const int* __restrict__ offN,
                                int* __restrict__ cursE, int* __restrict__ cursN,
                                int* __restrict__ srcA, float* __restrict__ cfA,
                                int* __restrict__ srcB, float* __restrict__ cfB, int M) {
  int m = blockIdx.x * 256 + threadIdx.x;
  if (m >= M) return;
  int r = ROW[m], c = COL[m];
  float nm = HD[c] * ND[r];
  float e = EWf[m];
  int p = offE[c] + atomicAdd(cursE + c, 1);
  srcA[p] = r; cfA[p] = e * nm;
  int q = offN[r] + atomicAdd(cursN + r, 1);
  srcB[q] = c; cfB[q] = WMf[c] * e * nm;
}

// ---- GEMM: out_bf16[N,128] = A[N,K] @ W[K,128] + bias ----
__global__ __launch_bounds__(256) void gemm_kernel(
    const void* __restrict__ Aptr, const float* __restrict__ W,
    const float* __restrict__ bias, unsigned short* __restrict__ out,
    int Nrows, int K, const int* __restrict__ flags, int relu) {
  __shared__ float xs[32][68];
  __shared__ float ws[32][128];
  const int tid = threadIdx.x;
  const int tx = tid & 15, ty = tid >> 4;
  const int rowBase = blockIdx.x * 64;
  const int abf16 = flags ? flags[0] : 1;
  float acc[4][8];
#pragma unroll
  for (int i = 0; i < 4; ++i)
#pragma unroll
    for (int j = 0; j < 8; ++j) acc[i][j] = 0.f;

  const int lr = tid >> 2;
  const int lk = (tid & 3) << 3;
  const int wkr = tid >> 3;
  const int wc = (tid & 7) << 4;

  for (int k0 = 0; k0 < K; k0 += 32) {
    float v[8];
    const int gr = rowBase + lr;
    if (gr < Nrows) {
      if (abf16) {
        us8 u = *reinterpret_cast<const us8*>(
            (const unsigned short*)Aptr + (size_t)gr * K + k0 + lk);
#pragma unroll
        for (int j = 0; j < 8; ++j) v[j] = bf2f(u[j]);
      } else {
        const float* A = (const float*)Aptr + (size_t)gr * K + k0 + lk;
        f4 u0 = *reinterpret_cast<const f4*>(A);
        f4 u1 = *reinterpret_cast<const f4*>(A + 4);
#pragma unroll
        for (int j = 0; j < 4; ++j) { v[j] = u0[j]; v[4 + j] = u1[j]; }
      }
    } else {
#pragma unroll
      for (int j = 0; j < 8; ++j) v[j] = 0.f;
    }
#pragma unroll
    for (int j = 0; j < 8; ++j) xs[lk + j][lr] = v[j];

    const float* Wp = W + (size_t)(k0 + wkr) * 128 + wc;
    f4 w0 = *reinterpret_cast<const f4*>(Wp);
    f4 w1 = *reinterpret_cast<const f4*>(Wp + 4);
    f4 w2 = *reinterpret_cast<const f4*>(Wp + 8);
    f4 w3 = *reinterpret_cast<const f4*>(Wp + 12);
    *reinterpret_cast<f4*>(&ws[wkr][wc])      = w0;
    *reinterpret_cast<f4*>(&ws[wkr][wc + 4])  = w1;
    *reinterpret_cast<f4*>(&ws[wkr][wc + 8])  = w2;
    *reinterpret_cast<f4*>(&ws[wkr][wc + 12]) = w3;
    __syncthreads();
#pragma unroll 8
    for (int k = 0; k < 32; ++k) {
      f4 a0 = *reinterpret_cast<const f4*>(&xs[k][ty << 2]);
      f4 b0 = *reinterpret_cast<const f4*>(&ws[k][tx << 2]);
      f4 b1 = *reinterpret_cast<const f4*>(&ws[k][64 + (tx << 2)]);
#pragma unroll
      for (int i = 0; i < 4; ++i) {
#pragma unroll
        for (int j = 0; j < 4; ++j) {
          acc[i][j]     += a0[i] * b0[j];
          acc[i][j + 4] += a0[i] * b1[j];
        }
      }
    }
    __syncthreads();
  }
  float bv[8];
#pragma unroll
  for (int j = 0; j < 4; ++j) {
    bv[j]     = bias[(tx << 2) + j];
    bv[4 + j] = bias[64 + (tx << 2) + j];
  }
#pragma unroll
  for (int i = 0; i < 4; ++i) {
    int gr = rowBase + (ty << 2) + i;
    if (gr >= Nrows) continue;
    us4 o0, o1;
#pragma unroll
    for (int j = 0; j < 4; ++j) {
      float s0 = acc[i][j] + bv[j];
      float s1 = acc[i][j + 4] + bv[j + 4];
      if (relu) { s0 = fmaxf(s0, 0.f); s1 = fmaxf(s1, 0.f); }
      o0[j] = f2bf(s0); o1[j] = f2bf(s1);
    }
    *reinterpret_cast<us4*>(out + (size_t)gr * 128 + (tx << 2))      = o0;
    *reinterpret_cast<us4*>(out + (size_t)gr * 128 + 64 + (tx << 2)) = o1;
  }
}

// ---- gather: out[seg,:] = sum_k cf[k] * X[src[k],:]  (one wave per segment) ----
__global__ __launch_bounds__(256) void gather_edge_kernel(
    const int* __restrict__ off, const int* __restrict__ src,
    const float* __restrict__ cf, const unsigned short* __restrict__ X,
    unsigned short* __restrict__ out, int nseg) {
  int seg = blockIdx.x * 4 + (threadIdx.x >> 6);
  if (seg >= nseg) return;
  int d = (threadIdx.x & 63) << 1;
  int k0 = off[seg], k1 = off[seg + 1];
  float a0 = 0.f, a1 = 0.f;
  for (int k = k0; k < k1; ++k) {
    int s = src[k];
    float c = cf[k];
    us2 v = *reinterpret_cast<const us2*>(X + (size_t)s * 128 + d);
    a0 += c * bf2f(v[0]);
    a1 += c * bf2f(v[1]);
  }
  us2 o; o[0] = f2bf(a0); o[1] = f2bf(a1);
  *reinterpret_cast<us2*>(out + (size_t)seg * 128 + d) = o;
}

// ---- gather + h = relu(h + z); writes bf16 (intermediate) or fp32 (d_out) ----
__global__ __launch_bounds__(256) void gather_node_relu_kernel(
    const int* __restrict__ off, const int* __restrict__ src,
    const float* __restrict__ cf, const unsigned short* __restrict__ HF,
    const unsigned short* __restrict__ H, void* __restrict__ out,
    int nseg, int outF32) {
  int seg = blockIdx.x * 4 + (threadIdx.x >> 6);
  if (seg >= nseg) return;
  int d = (threadIdx.x & 63) << 1;
  int k0 = off[seg], k1 = off[seg + 1];
  float a0 = 0.f, a1 = 0.f;
  for (int k = k0; k < k1; ++k) {
    int s = src[k];
    float c = cf[k];
    us2 v = *reinterpret_cast<const us2*>(HF + (size_t)s * 128 + d);
    a0 += c * bf2f(v[0]);
    a1 += c * bf2f(v[1]);
  }
  us2 h = *reinterpret_cast<const us2*>(H + (size_t)seg * 128 + d);
  float r0 = fmaxf(bf2f(h[0]) + a0, 0.f);
  float r1 = fmaxf(bf2f(h[1]) + a1, 0.f);
  if (outF32) {
    f2 o; o[0] = r0; o[1] = r1;
    *reinterpret_cast<f2*>((float*)out + (size_t)seg * 128 + d) = o;
  } else {
    us2 o; o[0] = f2bf(r0); o[1] = f2bf(r1);
    *reinterpret_cast<us2*>((unsigned short*)out + (size_t)seg * 128 + d) = o;
  }
}

extern "C" void kernel_launch(void* const* d_in, const int* in_sizes, int n_in,
                              void* d_out, int out_size, void* d_ws, size_t ws_size,
                              hipStream_t stream) {
  const void* x   = d_in[0];
  const void* hei = d_in[1];
  const void* wM  = d_in[2];
  const void* ew  = d_in[3];
  const void* fcw = d_in[4];
  const void* fcb = d_in[5];
  const void* cw  = d_in[6];
  const void* cb  = d_in[7];

  const int IN_DIM = 256, D = 128;
  const int N = in_sizes[0] / IN_DIM;
  const int M = in_sizes[1] / 2;
  const int E = in_sizes[2];
  const int L = in_sizes[6] / (D * D);

  float* w = (float*)d_ws;
  size_t o = 0;
  auto alloc = [&](size_t n) { float* p = w + o; o += (n + 3) & ~(size_t)3; return p; };

  unsigned short* H  = (unsigned short*)alloc((size_t)N * D / 2);
  unsigned short* XT = (unsigned short*)alloc((size_t)N * D / 2);
  unsigned short* HF = (unsigned short*)alloc((size_t)E * D / 2);
  int*   ROW  = (int*)alloc(M);     // ROW,COL contiguous (one cvt over 2M)
  int*   COL  = (int*)alloc(M);
  int*   srcA = (int*)alloc(M);
  float* cfA  = alloc(M);
  int*   srcB = (int*)alloc(M);
  float* cfB  = alloc(M);
  float* EWf  = alloc(M);
  int*   cursE = (int*)alloc(E);    // cursE,cursN contiguous (one memset)
  int*   cursN = (int*)alloc(N);
  float* ND   = alloc(N);           // ND,HD contiguous (one memset)
  float* HD   = alloc(E);
  int*   offE = (int*)alloc(E + 1);
  int*   offN = (int*)alloc(N + 1);
  float* WMf  = alloc(E);
  float* FCW  = alloc((size_t)IN_DIM * D);
  float* FCB  = alloc(D);
  float* CWf  = alloc((size_t)L * D * D);
  float* CBf  = alloc((size_t)L * D);
  int*   FLAGS = (int*)alloc(16);
  // total ~14.8M floats ~= 59 MB

  detect_kernel<<<1, 64, 0, stream>>>((const unsigned int*)x, (const unsigned int*)hei, FLAGS);

  cvt_idx<<<(2 * M + 255) / 256, 256, 0, stream>>>(hei, ROW, 2 * M, FLAGS);
  cvt_f32<<<(E + 255) / 256, 256, 0, stream>>>(wM, WMf, E, FLAGS);
  cvt_f32<<<(M + 255) / 256, 256, 0, stream>>>(ew, EWf, M, FLAGS);
  cvt_f32<<<(IN_DIM * D + 255) / 256, 256, 0, stream>>>(fcw, FCW, IN_DIM * D, FLAGS);
  cvt_f32<<<1, 256, 0, stream>>>(fcb, FCB, D, FLAGS);
  cvt_f32<<<(L * D * D + 255) / 256, 256, 0, stream>>>(cw, CWf, L * D * D, FLAGS);
  cvt_f32<<<(L * D + 255) / 256, 256, 0, stream>>>(cb, CBf, L * D, FLAGS);

  hipMemsetAsync(ND, 0, (size_t)(N + E) * sizeof(float), stream);
  deg_kernel<<<(M + 255) / 256, 256, 0, stream>>>(ROW, COL, WMf, EWf, ND, HD, M);
  {
    int mx = N > E ? N : E;
    finish_deg_kernel<<<(mx + 255) / 256, 256, 0, stream>>>(ND, HD, N, E);
  }

  hipMemsetAsync(cursE, 0, (size_t)(E + N) * sizeof(int), stream);
  hist_kernel<<<(M + 255) / 256, 256, 0, stream>>>(ROW, COL, cursE, cursN, M);
  scan_kernel<<<1, 1024, 0, stream>>>(cursE, offE, E);
  scan_kernel<<<1, 1024, 0, stream>>>(cursN, offN, N);
  hipMemsetAsync(cursE, 0, (size_t)(E + N) * sizeof(int), stream);
  permfill_kernel<<<(M + 255) / 256, 256, 0, stream>>>(ROW, COL, WMf, EWf, ND, HD,
                                                       offE, offN, cursE, cursN,
                                                       srcA, cfA, srcB, cfB, M);

  // h0 = relu(x @ fc_w + fc_b)
  gemm_kernel<<<(N + 63) / 64, 256, 0, stream>>>(x, FCW, FCB, H, N, IN_DIM, FLAGS, 1);

  int segBlkE = (E + 3) / 4, segBlkN = (N + 3) / 4;
  for (int l = 0; l < L; ++l) {
    gemm_kernel<<<(N + 63) / 64, 256, 0, stream>>>(H, CWf + (size_t)l * D * D,
                                                   CBf + (size_t)l * D, XT, N, D,
                                                   (const int*)nullptr, 0);
    gather_edge_kernel<<<segBlkE, 256, 0, stream>>>(offE, srcA, cfA, XT, HF, E);
    gather_node_relu_kernel<<<segBlkN, 256, 0, stream>>>(
        offN, srcB, cfB, HF, H,
        (l == L - 1) ? d_out : (void*)H, N, (l == L - 1) ? 1 : 0);
  }
}

// Round 4
// 777.132 us; speedup vs baseline: 1.2160x; 1.2160x over previous
//
#include <hip/hip_runtime.h>
#include <hip/hip_bf16.h>
#include <stdint.h>

typedef __attribute__((ext_vector_type(4))) float f4;
typedef __attribute__((ext_vector_type(2))) float f2;
typedef __attribute__((ext_vector_type(8))) unsigned short us8;
typedef __attribute__((ext_vector_type(4))) unsigned short us4;
typedef __attribute__((ext_vector_type(2))) unsigned short us2;

__device__ __forceinline__ float bf2f(unsigned short u) {
  union { unsigned int i; float f; } t; t.i = ((unsigned int)u) << 16; return t.f;
}
__device__ __forceinline__ unsigned short f2bf(float f) {
  union { float f; unsigned int i; } t; t.f = f;
  unsigned int u = t.i;
  return (unsigned short)((u + 0x7FFFu + ((u >> 16) & 1u)) >> 16);
}

// ---- dtype detection ----
__global__ void detect_kernel(const unsigned int* __restrict__ xb,
                              const unsigned int* __restrict__ ib,
                              int* __restrict__ flags) {
  if (threadIdx.x == 0) {
    int cnt = 0;
    for (int i = 0; i < 256; ++i) {
      unsigned int e = (xb[i] >> 7) & 0xffu;
      if (e >= 110u && e <= 135u) ++cnt;
    }
    flags[0] = (cnt >= 180) ? 1 : 0;
    int zc = 0;
    for (int i = 0; i < 128; ++i) if (ib[2 * i + 1] == 0u) ++zc;
    flags[1] = (zc >= 120) ? 1 : 0;
  }
}

__global__ void cvt_f32(const void* __restrict__ src, float* __restrict__ dst,
                        int n, const int* __restrict__ flags) {
  int i = blockIdx.x * 256 + threadIdx.x;
  if (i >= n) return;
  if (flags[0]) dst[i] = bf2f(((const unsigned short*)src)[i]);
  else          dst[i] = ((const float*)src)[i];
}

__global__ void cvt_idx(const void* __restrict__ src, int* __restrict__ dst,
                        int n, const int* __restrict__ flags) {
  int i = blockIdx.x * 256 + threadIdx.x;
  if (i >= n) return;
  if (flags[1]) dst[i] = (int)(((const long long*)src)[i]);
  else          dst[i] = ((const int*)src)[i];
}

// ---- degrees + CSR histogram (merged: one pass over ROW/COL) ----
__global__ void deg_hist_kernel(const int* __restrict__ row, const int* __restrict__ col,
                                const float* __restrict__ wM, const float* __restrict__ ew,
                                float* __restrict__ nd, float* __restrict__ hd,
                                int* __restrict__ cntE, int* __restrict__ cntN, int M) {
  int m = blockIdx.x * 256 + threadIdx.x;
  if (m >= M) return;
  int r = row[m], c = col[m];
  atomicAdd(nd + r, wM[c]);
  atomicAdd(hd + c, ew[m]);
  atomicAdd(cntE + c, 1);
  atomicAdd(cntN + r, 1);
}

__global__ void finish_deg_kernel(float* __restrict__ nd, float* __restrict__ hd,
                                  int N, int E) {
  int i = blockIdx.x * 256 + threadIdx.x;
  if (i < N) nd[i] = rsqrtf(nd[i] + 1e-8f);
  if (i < E) hd[i] = rsqrtf(hd[i] + 1e-8f);
}

// ---- multi-block 3-phase exclusive scan ----
__global__ __launch_bounds__(256) void scan_p1(const int* __restrict__ cnt,
                                               int* __restrict__ bsum, int n) {
  __shared__ int s[256];
  int i = blockIdx.x * 256 + threadIdx.x;
  s[threadIdx.x] = (i < n) ? cnt[i] : 0;
  __syncthreads();
  for (int st = 128; st > 0; st >>= 1) {
    if (threadIdx.x < st) s[threadIdx.x] += s[threadIdx.x + st];
    __syncthreads();
  }
  if (threadIdx.x == 0) bsum[blockIdx.x] = s[0];
}

// single block, nb <= 1024: in-place exclusive scan of bsum, bsum[nb] = total
__global__ __launch_bounds__(1024) void scan_p2(int* __restrict__ bsum, int nb) {
  __shared__ int buf[1024];
  int tid = threadIdx.x;
  int v = (tid < nb) ? bsum[tid] : 0;
  buf[tid] = v;
  __syncthreads();
  for (int s = 1; s < 1024; s <<= 1) {
    int t = (tid >= s) ? buf[tid - s] : 0;
    __syncthreads();
    buf[tid] += t;
    __syncthreads();
  }
  if (tid < nb) bsum[tid] = buf[tid] - v;
  if (tid == 0) bsum[nb] = buf[1023];
}

__global__ __launch_bounds__(256) void scan_p3(const int* __restrict__ cnt,
                                               const int* __restrict__ bsum,
                                               int* __restrict__ off, int n) {
  __shared__ int buf[256];
  int i = blockIdx.x * 256 + threadIdx.x;
  int v = (i < n) ? cnt[i] : 0;
  buf[threadIdx.x] = v;
  __syncthreads();
  for (int s = 1; s < 256; s <<= 1) {
    int t = (threadIdx.x >= s) ? buf[threadIdx.x - s] : 0;
    __syncthreads();
    buf[threadIdx.x] += t;
    __syncthreads();
  }
  if (i < n) off[i] = bsum[blockIdx.x] + buf[threadIdx.x] - v;
  if (i == 0) off[n] = bsum[gridDim.x];
}

__global__ void permfill_kernel(const int* __restrict__ ROW, const int* __restrict__ COL,
                                const float* __restrict__ WMf, const float* __restrict__ EWf,
                                const float* __restrict__ ND, const float* __restrict__ HD,
                                const int* __restrict__ offE, const int* __restrict__ offN,
                                int* __restrict__ cursE, int* __restrict__ cursN,
                                int* __restrict__ srcA, float* __restrict__ cfA,
                                int* __restrict__ srcB, float* __restrict__ cfB, int M) {
  int m = blockIdx.x * 256 + threadIdx.x;
  if (m >= M) return;
  int r = ROW[m], c = COL[m];
  float nm = HD[c] * ND[r];
  float e = EWf[m];
  int p = offE[c] + atomicAdd(cursE + c, 1);
  srcA[p] = r; cfA[p] = e * nm;
  int q = offN[r] + atomicAdd(cursN + r, 1);
  srcB[q] = c; cfB[q] = WMf[c] * e * nm;
}

// ---- GEMM: out_bf16[N,128] = A[N,K] @ W[K,128] + bias ----
__global__ __launch_bounds__(256) void gemm_kernel(
    const void* __restrict__ Aptr, const float* __restrict__ W,
    const float* __restrict__ bias, unsigned short* __restrict__ out,
    int Nrows, int K, const int* __restrict__ flags, int relu) {
  __shared__ float xs[32][68];
  __shared__ float ws[32][128];
  const int tid = threadIdx.x;
  const int tx = tid & 15, ty = tid >> 4;
  const int rowBase = blockIdx.x * 64;
  const int abf16 = flags ? flags[0] : 1;
  float acc[4][8];
#pragma unroll
  for (int i = 0; i < 4; ++i)
#pragma unroll
    for (int j = 0; j < 8; ++j) acc[i][j] = 0.f;

  const int lr = tid >> 2;
  const int lk = (tid & 3) << 3;
  const int wkr = tid >> 3;
  const int wc = (tid & 7) << 4;

  for (int k0 = 0; k0 < K; k0 += 32) {
    float v[8];
    const int gr = rowBase + lr;
    if (gr < Nrows) {
      if (abf16) {
        us8 u = *reinterpret_cast<const us8*>(
            (const unsigned short*)Aptr + (size_t)gr * K + k0 + lk);
#pragma unroll
        for (int j = 0; j < 8; ++j) v[j] = bf2f(u[j]);
      } else {
        const float* A = (const float*)Aptr + (size_t)gr * K + k0 + lk;
        f4 u0 = *reinterpret_cast<const f4*>(A);
        f4 u1 = *reinterpret_cast<const f4*>(A + 4);
#pragma unroll
        for (int j = 0; j < 4; ++j) { v[j] = u0[j]; v[4 + j] = u1[j]; }
      }
    } else {
#pragma unroll
      for (int j = 0; j < 8; ++j) v[j] = 0.f;
    }
#pragma unroll
    for (int j = 0; j < 8; ++j) xs[lk + j][lr] = v[j];

    const float* Wp = W + (size_t)(k0 + wkr) * 128 + wc;
    f4 w0 = *reinterpret_cast<const f4*>(Wp);
    f4 w1 = *reinterpret_cast<const f4*>(Wp + 4);
    f4 w2 = *reinterpret_cast<const f4*>(Wp + 8);
    f4 w3 = *reinterpret_cast<const f4*>(Wp + 12);
    *reinterpret_cast<f4*>(&ws[wkr][wc])      = w0;
    *reinterpret_cast<f4*>(&ws[wkr][wc + 4])  = w1;
    *reinterpret_cast<f4*>(&ws[wkr][wc + 8])  = w2;
    *reinterpret_cast<f4*>(&ws[wkr][wc + 12]) = w3;
    __syncthreads();
#pragma unroll 8
    for (int k = 0; k < 32; ++k) {
      f4 a0 = *reinterpret_cast<const f4*>(&xs[k][ty << 2]);
      f4 b0 = *reinterpret_cast<const f4*>(&ws[k][tx << 2]);
      f4 b1 = *reinterpret_cast<const f4*>(&ws[k][64 + (tx << 2)]);
#pragma unroll
      for (int i = 0; i < 4; ++i) {
#pragma unroll
        for (int j = 0; j < 4; ++j) {
          acc[i][j]     += a0[i] * b0[j];
          acc[i][j + 4] += a0[i] * b1[j];
        }
      }
    }
    __syncthreads();
  }
  float bv[8];
#pragma unroll
  for (int j = 0; j < 4; ++j) {
    bv[j]     = bias[(tx << 2) + j];
    bv[4 + j] = bias[64 + (tx << 2) + j];
  }
#pragma unroll
  for (int i = 0; i < 4; ++i) {
    int gr = rowBase + (ty << 2) + i;
    if (gr >= Nrows) continue;
    us4 o0, o1;
#pragma unroll
    for (int j = 0; j < 4; ++j) {
      float s0 = acc[i][j] + bv[j];
      float s1 = acc[i][j + 4] + bv[j + 4];
      if (relu) { s0 = fmaxf(s0, 0.f); s1 = fmaxf(s1, 0.f); }
      o0[j] = f2bf(s0); o1[j] = f2bf(s1);
    }
    *reinterpret_cast<us4*>(out + (size_t)gr * 128 + (tx << 2))      = o0;
    *reinterpret_cast<us4*>(out + (size_t)gr * 128 + 64 + (tx << 2)) = o1;
  }
}

// ---- gather: out[seg,:] = sum_k cf[k] * X[src[k],:]  (one wave per segment) ----
__global__ __launch_bounds__(256) void gather_edge_kernel(
    const int* __restrict__ off, const int* __restrict__ src,
    const float* __restrict__ cf, const unsigned short* __restrict__ X,
    unsigned short* __restrict__ out, int nseg) {
  int seg = blockIdx.x * 4 + (threadIdx.x >> 6);
  if (seg >= nseg) return;
  int d = (threadIdx.x & 63) << 1;
  int k0 = off[seg], k1 = off[seg + 1];
  float a0 = 0.f, a1 = 0.f;
  for (int k = k0; k < k1; ++k) {
    int s = src[k];
    float c = cf[k];
    us2 v = *reinterpret_cast<const us2*>(X + (size_t)s * 128 + d);
    a0 += c * bf2f(v[0]);
    a1 += c * bf2f(v[1]);
  }
  us2 o; o[0] = f2bf(a0); o[1] = f2bf(a1);
  *reinterpret_cast<us2*>(out + (size_t)seg * 128 + d) = o;
}

// ---- gather + h = relu(h + z); writes bf16 (intermediate) or fp32 (d_out) ----
__global__ __launch_bounds__(256) void gather_node_relu_kernel(
    const int* __restrict__ off, const int* __restrict__ src,
    const float* __restrict__ cf, const unsigned short* __restrict__ HF,
    const unsigned short* __restrict__ H, void* __restrict__ out,
    int nseg, int outF32) {
  int seg = blockIdx.x * 4 + (threadIdx.x >> 6);
  if (seg >= nseg) return;
  int d = (threadIdx.x & 63) << 1;
  int k0 = off[seg], k1 = off[seg + 1];
  float a0 = 0.f, a1 = 0.f;
  for (int k = k0; k < k1; ++k) {
    int s = src[k];
    float c = cf[k];
    us2 v = *reinterpret_cast<const us2*>(HF + (size_t)s * 128 + d);
    a0 += c * bf2f(v[0]);
    a1 += c * bf2f(v[1]);
  }
  us2 h = *reinterpret_cast<const us2*>(H + (size_t)seg * 128 + d);
  float r0 = fmaxf(bf2f(h[0]) + a0, 0.f);
  float r1 = fmaxf(bf2f(h[1]) + a1, 0.f);
  if (outF32) {
    f2 o; o[0] = r0; o[1] = r1;
    *reinterpret_cast<f2*>((float*)out + (size_t)seg * 128 + d) = o;
  } else {
    us2 o; o[0] = f2bf(r0); o[1] = f2bf(r1);
    *reinterpret_cast<us2*>((unsigned short*)out + (size_t)seg * 128 + d) = o;
  }
}

extern "C" void kernel_launch(void* const* d_in, const int* in_sizes, int n_in,
                              void* d_out, int out_size, void* d_ws, size_t ws_size,
                              hipStream_t stream) {
  const void* x   = d_in[0];
  const void* hei = d_in[1];
  const void* wM  = d_in[2];
  const void* ew  = d_in[3];
  const void* fcw = d_in[4];
  const void* fcb = d_in[5];
  const void* cw  = d_in[6];
  const void* cb  = d_in[7];

  const int IN_DIM = 256, D = 128;
  const int N = in_sizes[0] / IN_DIM;
  const int M = in_sizes[1] / 2;
  const int E = in_sizes[2];
  const int L = in_sizes[6] / (D * D);

  float* w = (float*)d_ws;
  size_t o = 0;
  auto alloc = [&](size_t n) { float* p = w + o; o += (n + 3) & ~(size_t)3; return p; };

  unsigned short* H  = (unsigned short*)alloc((size_t)N * D / 2);
  unsigned short* XT = (unsigned short*)alloc((size_t)N * D / 2);
  unsigned short* HF = (unsigned short*)alloc((size_t)E * D / 2);
  int*   ROW  = (int*)alloc(M);
  int*   COL  = (int*)alloc(M);
  int*   srcA = (int*)alloc(M);
  float* cfA  = alloc(M);
  int*   srcB = (int*)alloc(M);
  float* cfB  = alloc(M);
  float* EWf  = alloc(M);
  int*   cursE = (int*)alloc(E);    // cursE,cursN contiguous (one memset)
  int*   cursN = (int*)alloc(N);
  float* ND   = alloc(N);           // ND,HD contiguous (one memset)
  float* HD   = alloc(E);
  int*   offE = (int*)alloc(E + 1);
  int*   offN = (int*)alloc(N + 1);
  float* WMf  = alloc(E);
  float* FCW  = alloc((size_t)IN_DIM * D);
  float* FCB  = alloc(D);
  float* CWf  = alloc((size_t)L * D * D);
  float* CBf  = alloc((size_t)L * D);
  int*   BSE  = (int*)alloc(1026);  // block sums for scans (<=1025 entries)
  int*   BSN  = (int*)alloc(1026);
  int*   FLAGS = (int*)alloc(16);

  detect_kernel<<<1, 64, 0, stream>>>((const unsigned int*)x, (const unsigned int*)hei, FLAGS);

  cvt_idx<<<(2 * M + 255) / 256, 256, 0, stream>>>(hei, ROW, 2 * M, FLAGS);
  cvt_f32<<<(E + 255) / 256, 256, 0, stream>>>(wM, WMf, E, FLAGS);
  cvt_f32<<<(M + 255) / 256, 256, 0, stream>>>(ew, EWf, M, FLAGS);
  cvt_f32<<<(IN_DIM * D + 255) / 256, 256, 0, stream>>>(fcw, FCW, IN_DIM * D, FLAGS);
  cvt_f32<<<1, 256, 0, stream>>>(fcb, FCB, D, FLAGS);
  cvt_f32<<<(L * D * D + 255) / 256, 256, 0, stream>>>(cw, CWf, L * D * D, FLAGS);
  cvt_f32<<<(L * D + 255) / 256, 256, 0, stream>>>(cb, CBf, L * D, FLAGS);

  hipMemsetAsync(ND, 0, (size_t)(N + E) * sizeof(float), stream);
  hipMemsetAsync(cursE, 0, (size_t)(E + N) * sizeof(int), stream);
  deg_hist_kernel<<<(M + 255) / 256, 256, 0, stream>>>(ROW, COL, WMf, EWf, ND, HD,
                                                       cursE, cursN, M);
  {
    int mx = N > E ? N : E;
    finish_deg_kernel<<<(mx + 255) / 256, 256, 0, stream>>>(ND, HD, N, E);
  }

  // multi-block scans: offE from cursE (counts), offN from cursN
  int nbE = (E + 255) / 256, nbN = (N + 255) / 256;
  scan_p1<<<nbE, 256, 0, stream>>>(cursE, BSE, E);
  scan_p2<<<1, 1024, 0, stream>>>(BSE, nbE);
  scan_p3<<<nbE, 256, 0, stream>>>(cursE, BSE, offE, E);
  scan_p1<<<nbN, 256, 0, stream>>>(cursN, BSN, N);
  scan_p2<<<1, 1024, 0, stream>>>(BSN, nbN);
  scan_p3<<<nbN, 256, 0, stream>>>(cursN, BSN, offN, N);

  hipMemsetAsync(cursE, 0, (size_t)(E + N) * sizeof(int), stream);
  permfill_kernel<<<(M + 255) / 256, 256, 0, stream>>>(ROW, COL, WMf, EWf, ND, HD,
                                                       offE, offN, cursE, cursN,
                                                       srcA, cfA, srcB, cfB, M);

  // h0 = relu(x @ fc_w + fc_b)
  gemm_kernel<<<(N + 63) / 64, 256, 0, stream>>>(x, FCW, FCB, H, N, IN_DIM, FLAGS, 1);

  int segBlkE = (E + 3) / 4, segBlkN = (N + 3) / 4;
  for (int l = 0; l < L; ++l) {
    gemm_kernel<<<(N + 63) / 64, 256, 0, stream>>>(H, CWf + (size_t)l * D * D,
                                                   CBf + (size_t)l * D, XT, N, D,
                                                   (const int*)nullptr, 0);
    gather_edge_kernel<<<segBlkE, 256, 0, stream>>>(offE, srcA, cfA, XT, HF, E);
    gather_node_relu_kernel<<<segBlkN, 256, 0, stream>>>(
        offN, srcB, cfB, HF, H,
        (l == L - 1) ? d_out : (void*)H, N, (l == L - 1) ? 1 : 0);
  }
}

// Round 5
// 547.862 us; speedup vs baseline: 1.7249x; 1.4185x over previous
//
#include <hip/hip_runtime.h>
#include <hip/hip_bf16.h>
#include <stdint.h>

typedef __attribute__((ext_vector_type(4))) float f4;
typedef __attribute__((ext_vector_type(2))) float f2;
typedef __attribute__((ext_vector_type(2))) int i2;
typedef __attribute__((ext_vector_type(8))) unsigned short us8;
typedef __attribute__((ext_vector_type(4))) unsigned short us4;
typedef __attribute__((ext_vector_type(2))) unsigned short us2;

__device__ __forceinline__ float bf2f(unsigned short u) {
  union { unsigned int i; float f; } t; t.i = ((unsigned int)u) << 16; return t.f;
}
__device__ __forceinline__ unsigned short f2bf(float f) {
  union { float f; unsigned int i; } t; t.f = f;
  unsigned int u = t.i;
  return (unsigned short)((u + 0x7FFFu + ((u >> 16) & 1u)) >> 16);
}

// ---- dtype detection ----
__global__ void detect_kernel(const unsigned int* __restrict__ xb,
                              const unsigned int* __restrict__ ib,
                              int* __restrict__ flags) {
  if (threadIdx.x == 0) {
    int cnt = 0;
    for (int i = 0; i < 256; ++i) {
      unsigned int e = (xb[i] >> 7) & 0xffu;
      if (e >= 110u && e <= 135u) ++cnt;
    }
    flags[0] = (cnt >= 180) ? 1 : 0;
    int zc = 0;
    for (int i = 0; i < 128; ++i) if (ib[2 * i + 1] == 0u) ++zc;
    flags[1] = (zc >= 120) ? 1 : 0;
  }
}

__global__ void cvt_f32(const void* __restrict__ src, float* __restrict__ dst,
                        int n, const int* __restrict__ flags) {
  int i = blockIdx.x * 256 + threadIdx.x;
  if (i >= n) return;
  if (flags[0]) dst[i] = bf2f(((const unsigned short*)src)[i]);
  else          dst[i] = ((const float*)src)[i];
}

// ---- index convert + edge-weight convert + CSR count histogram (one pass) ----
__global__ void cvt_idx_hist(const void* __restrict__ hei, const void* __restrict__ ew,
                             int M, int* __restrict__ ROW, int* __restrict__ COL,
                             float* __restrict__ EWf,
                             int* __restrict__ cntN, int* __restrict__ cntE,
                             const int* __restrict__ flags) {
  int m = blockIdx.x * 256 + threadIdx.x;
  if (m >= M) return;
  int r, c;
  if (flags[1]) {
    r = (int)((const long long*)hei)[m];
    c = (int)((const long long*)hei)[M + m];
  } else {
    r = ((const int*)hei)[m];
    c = ((const int*)hei)[M + m];
  }
  ROW[m] = r; COL[m] = c;
  EWf[m] = flags[0] ? bf2f(((const unsigned short*)ew)[m]) : ((const float*)ew)[m];
  atomicAdd(cntN + r, 1);
  atomicAdd(cntE + c, 1);
}

// ---- multi-block 3-phase exclusive scan ----
__global__ __launch_bounds__(256) void scan_p1(const int* __restrict__ cnt,
                                               int* __restrict__ bsum, int n) {
  __shared__ int s[256];
  int i = blockIdx.x * 256 + threadIdx.x;
  s[threadIdx.x] = (i < n) ? cnt[i] : 0;
  __syncthreads();
  for (int st = 128; st > 0; st >>= 1) {
    if (threadIdx.x < st) s[threadIdx.x] += s[threadIdx.x + st];
    __syncthreads();
  }
  if (threadIdx.x == 0) bsum[blockIdx.x] = s[0];
}

__global__ __launch_bounds__(1024) void scan_p2(int* __restrict__ bsum, int nb) {
  __shared__ int buf[1024];
  int tid = threadIdx.x;
  int v = (tid < nb) ? bsum[tid] : 0;
  buf[tid] = v;
  __syncthreads();
  for (int s = 1; s < 1024; s <<= 1) {
    int t = (tid >= s) ? buf[tid - s] : 0;
    __syncthreads();
    buf[tid] += t;
    __syncthreads();
  }
  if (tid < nb) bsum[tid] = buf[tid] - v;
  if (tid == 0) bsum[nb] = buf[1023];
}

__global__ __launch_bounds__(256) void scan_p3(const int* __restrict__ cnt,
                                               const int* __restrict__ bsum,
                                               int* __restrict__ off, int n) {
  __shared__ int buf[256];
  int i = blockIdx.x * 256 + threadIdx.x;
  int v = (i < n) ? cnt[i] : 0;
  buf[threadIdx.x] = v;
  __syncthreads();
  for (int s = 1; s < 256; s <<= 1) {
    int t = (threadIdx.x >= s) ? buf[threadIdx.x - s] : 0;
    __syncthreads();
    buf[threadIdx.x] += t;
    __syncthreads();
  }
  if (i < n) off[i] = bsum[blockIdx.x] + buf[threadIdx.x] - v;
  if (i == 0) off[n] = bsum[gridDim.x];
}

// ---- CSR fill: 8-byte (src, ew) entries; coefficients are just ew[m] ----
__global__ void permfill2(const int* __restrict__ ROW, const int* __restrict__ COL,
                          const float* __restrict__ EWf,
                          const int* __restrict__ offE, const int* __restrict__ offN,
                          int* __restrict__ cursE, int* __restrict__ cursN,
                          i2* __restrict__ ENTA, i2* __restrict__ ENTB, int M) {
  int m = blockIdx.x * 256 + threadIdx.x;
  if (m >= M) return;
  int r = ROW[m], c = COL[m];
  int e = __float_as_int(EWf[m]);
  int p = offE[c] + atomicAdd(cursE + c, 1);
  i2 ea; ea[0] = r; ea[1] = e; ENTA[p] = ea;
  int q = offN[r] + atomicAdd(cursN + r, 1);
  i2 eb; eb[0] = c; eb[1] = e; ENTB[q] = eb;
}

// ---- degrees from CSR (no atomics) ----
// sc_e[c] = wM[c] / (hyper_deg[c] + 1e-8)   (== wM * hd^2)
__global__ void degE_kernel(const i2* __restrict__ ENTA, const int* __restrict__ offE,
                            const float* __restrict__ WMf, float* __restrict__ sc_e, int E) {
  int c = blockIdx.x * 256 + threadIdx.x;
  if (c >= E) return;
  int k0 = offE[c], k1 = offE[c + 1];
  float s = 0.f;
  for (int k = k0; k < k1; ++k) s += __int_as_float(ENTA[k][1]);
  sc_e[c] = WMf[c] / (s + 1e-8f);
}

// nd[r] = rsqrt(node_deg[r] + 1e-8)
__global__ void degN_kernel(const i2* __restrict__ ENTB, const int* __restrict__ offN,
                            const float* __restrict__ WMf, float* __restrict__ nd, int N) {
  int r = blockIdx.x * 256 + threadIdx.x;
  if (r >= N) return;
  int k0 = offN[r], k1 = offN[r + 1];
  float s = 0.f;
  for (int k = k0; k < k1; ++k) s += WMf[ENTB[k][0]];
  nd[r] = rsqrtf(s + 1e-8f);
}

// ---- GEMM: out_bf16[N,128] = rowScale[r] * (A[N,K] @ W[K,128] + bias) ----
__global__ __launch_bounds__(256) void gemm_kernel(
    const void* __restrict__ Aptr, const float* __restrict__ W,
    const float* __restrict__ bias, unsigned short* __restrict__ out,
    int Nrows, int K, const int* __restrict__ flags, int relu,
    const float* __restrict__ rowScale) {
  __shared__ float xs[32][68];
  __shared__ float ws[32][128];
  const int tid = threadIdx.x;
  const int tx = tid & 15, ty = tid >> 4;
  const int rowBase = blockIdx.x * 64;
  const int abf16 = flags ? flags[0] : 1;
  float acc[4][8];
#pragma unroll
  for (int i = 0; i < 4; ++i)
#pragma unroll
    for (int j = 0; j < 8; ++j) acc[i][j] = 0.f;

  const int lr = tid >> 2;
  const int lk = (tid & 3) << 3;
  const int wkr = tid >> 3;
  const int wc = (tid & 7) << 4;

  for (int k0 = 0; k0 < K; k0 += 32) {
    float v[8];
    const int gr = rowBase + lr;
    if (gr < Nrows) {
      if (abf16) {
        us8 u = *reinterpret_cast<const us8*>(
            (const unsigned short*)Aptr + (size_t)gr * K + k0 + lk);
#pragma unroll
        for (int j = 0; j < 8; ++j) v[j] = bf2f(u[j]);
      } else {
        const float* A = (const float*)Aptr + (size_t)gr * K + k0 + lk;
        f4 u0 = *reinterpret_cast<const f4*>(A);
        f4 u1 = *reinterpret_cast<const f4*>(A + 4);
#pragma unroll
        for (int j = 0; j < 4; ++j) { v[j] = u0[j]; v[4 + j] = u1[j]; }
      }
    } else {
#pragma unroll
      for (int j = 0; j < 8; ++j) v[j] = 0.f;
    }
#pragma unroll
    for (int j = 0; j < 8; ++j) xs[lk + j][lr] = v[j];

    const float* Wp = W + (size_t)(k0 + wkr) * 128 + wc;
    f4 w0 = *reinterpret_cast<const f4*>(Wp);
    f4 w1 = *reinterpret_cast<const f4*>(Wp + 4);
    f4 w2 = *reinterpret_cast<const f4*>(Wp + 8);
    f4 w3 = *reinterpret_cast<const f4*>(Wp + 12);
    *reinterpret_cast<f4*>(&ws[wkr][wc])      = w0;
    *reinterpret_cast<f4*>(&ws[wkr][wc + 4])  = w1;
    *reinterpret_cast<f4*>(&ws[wkr][wc + 8])  = w2;
    *reinterpret_cast<f4*>(&ws[wkr][wc + 12]) = w3;
    __syncthreads();
#pragma unroll 8
    for (int k = 0; k < 32; ++k) {
      f4 a0 = *reinterpret_cast<const f4*>(&xs[k][ty << 2]);
      f4 b0 = *reinterpret_cast<const f4*>(&ws[k][tx << 2]);
      f4 b1 = *reinterpret_cast<const f4*>(&ws[k][64 + (tx << 2)]);
#pragma unroll
      for (int i = 0; i < 4; ++i) {
#pragma unroll
        for (int j = 0; j < 4; ++j) {
          acc[i][j]     += a0[i] * b0[j];
          acc[i][j + 4] += a0[i] * b1[j];
        }
      }
    }
    __syncthreads();
  }
  float bv[8];
#pragma unroll
  for (int j = 0; j < 4; ++j) {
    bv[j]     = bias[(tx << 2) + j];
    bv[4 + j] = bias[64 + (tx << 2) + j];
  }
#pragma unroll
  for (int i = 0; i < 4; ++i) {
    int gr = rowBase + (ty << 2) + i;
    if (gr >= Nrows) continue;
    float sc = rowScale ? rowScale[gr] : 1.f;
    us4 o0, o1;
#pragma unroll
    for (int j = 0; j < 4; ++j) {
      float s0 = acc[i][j] + bv[j];
      float s1 = acc[i][j + 4] + bv[j + 4];
      if (relu) { s0 = fmaxf(s0, 0.f); s1 = fmaxf(s1, 0.f); }
      o0[j] = f2bf(s0 * sc); o1[j] = f2bf(s1 * sc);
    }
    *reinterpret_cast<us4*>(out + (size_t)gr * 128 + (tx << 2))      = o0;
    *reinterpret_cast<us4*>(out + (size_t)gr * 128 + 64 + (tx << 2)) = o1;
  }
}

// ---- gather A: HF[c,:] = sc_e[c] * sum_k ew_k * X[src_k,:]  (wave/segment, 4-unroll) ----
__global__ __launch_bounds__(256) void gather_edge2(
    const int* __restrict__ off, const i2* __restrict__ ENT,
    const float* __restrict__ sc_e, const unsigned short* __restrict__ X,
    unsigned short* __restrict__ out, int nseg) {
  int seg = blockIdx.x * 4 + (threadIdx.x >> 6);
  if (seg >= nseg) return;
  int d = (threadIdx.x & 63) << 1;
  int k0 = off[seg], k1 = off[seg + 1];
  float a0 = 0.f, a1 = 0.f;
  int k = k0;
  for (; k + 4 <= k1; k += 4) {
    i2 e0 = ENT[k], e1 = ENT[k + 1], e2 = ENT[k + 2], e3 = ENT[k + 3];
    us2 v0 = *reinterpret_cast<const us2*>(X + (size_t)e0[0] * 128 + d);
    us2 v1 = *reinterpret_cast<const us2*>(X + (size_t)e1[0] * 128 + d);
    us2 v2 = *reinterpret_cast<const us2*>(X + (size_t)e2[0] * 128 + d);
    us2 v3 = *reinterpret_cast<const us2*>(X + (size_t)e3[0] * 128 + d);
    float c0 = __int_as_float(e0[1]), c1 = __int_as_float(e1[1]);
    float c2 = __int_as_float(e2[1]), c3 = __int_as_float(e3[1]);
    a0 += c0 * bf2f(v0[0]); a1 += c0 * bf2f(v0[1]);
    a0 += c1 * bf2f(v1[0]); a1 += c1 * bf2f(v1[1]);
    a0 += c2 * bf2f(v2[0]); a1 += c2 * bf2f(v2[1]);
    a0 += c3 * bf2f(v3[0]); a1 += c3 * bf2f(v3[1]);
  }
  for (; k < k1; ++k) {
    i2 e = ENT[k];
    us2 v = *reinterpret_cast<const us2*>(X + (size_t)e[0] * 128 + d);
    float c = __int_as_float(e[1]);
    a0 += c * bf2f(v[0]); a1 += c * bf2f(v[1]);
  }
  float sc = sc_e[seg];
  us2 o; o[0] = f2bf(sc * a0); o[1] = f2bf(sc * a1);
  *reinterpret_cast<us2*>(out + (size_t)seg * 128 + d) = o;
}

// ---- gather B + h = relu(h + nd[r]*sum); bf16 (intermediate) or fp32 (d_out) ----
__global__ __launch_bounds__(256) void gather_node2(
    const int* __restrict__ off, const i2* __restrict__ ENT,
    const float* __restrict__ nd, const unsigned short* __restrict__ HF,
    const unsigned short* __restrict__ H, void* __restrict__ out,
    int nseg, int outF32) {
  int seg = blockIdx.x * 4 + (threadIdx.x >> 6);
  if (seg >= nseg) return;
  int d = (threadIdx.x & 63) << 1;
  int k0 = off[seg], k1 = off[seg + 1];
  float a0 = 0.f, a1 = 0.f;
  int k = k0;
  for (; k + 4 <= k1; k += 4) {
    i2 e0 = ENT[k], e1 = ENT[k + 1], e2 = ENT[k + 2], e3 = ENT[k + 3];
    us2 v0 = *reinterpret_cast<const us2*>(HF + (size_t)e0[0] * 128 + d);
    us2 v1 = *reinterpret_cast<const us2*>(HF + (size_t)e1[0] * 128 + d);
    us2 v2 = *reinterpret_cast<const us2*>(HF + (size_t)e2[0] * 128 + d);
    us2 v3 = *reinterpret_cast<const us2*>(HF + (size_t)e3[0] * 128 + d);
    float c0 = __int_as_float(e0[1]), c1 = __int_as_float(e1[1]);
    float c2 = __int_as_float(e2[1]), c3 = __int_as_float(e3[1]);
    a0 += c0 * bf2f(v0[0]); a1 += c0 * bf2f(v0[1]);
    a0 += c1 * bf2f(v1[0]); a1 += c1 * bf2f(v1[1]);
    a0 += c2 * bf2f(v2[0]); a1 += c2 * bf2f(v2[1]);
    a0 += c3 * bf2f(v3[0]); a1 += c3 * bf2f(v3[1]);
  }
  for (; k < k1; ++k) {
    i2 e = ENT[k];
    us2 v = *reinterpret_cast<const us2*>(HF + (size_t)e[0] * 128 + d);
    float c = __int_as_float(e[1]);
    a0 += c * bf2f(v[0]); a1 += c * bf2f(v[1]);
  }
  float s = nd[seg];
  us2 h = *reinterpret_cast<const us2*>(H + (size_t)seg * 128 + d);
  float r0 = fmaxf(bf2f(h[0]) + s * a0, 0.f);
  float r1 = fmaxf(bf2f(h[1]) + s * a1, 0.f);
  if (outF32) {
    f2 o; o[0] = r0; o[1] = r1;
    *reinterpret_cast<f2*>((float*)out + (size_t)seg * 128 + d) = o;
  } else {
    us2 o; o[0] = f2bf(r0); o[1] = f2bf(r1);
    *reinterpret_cast<us2*>((unsigned short*)out + (size_t)seg * 128 + d) = o;
  }
}

extern "C" void kernel_launch(void* const* d_in, const int* in_sizes, int n_in,
                              void* d_out, int out_size, void* d_ws, size_t ws_size,
                              hipStream_t stream) {
  const void* x   = d_in[0];
  const void* hei = d_in[1];
  const void* wM  = d_in[2];
  const void* ew  = d_in[3];
  const void* fcw = d_in[4];
  const void* fcb = d_in[5];
  const void* cw  = d_in[6];
  const void* cb  = d_in[7];

  const int IN_DIM = 256, D = 128;
  const int N = in_sizes[0] / IN_DIM;
  const int M = in_sizes[1] / 2;
  const int E = in_sizes[2];
  const int L = in_sizes[6] / (D * D);

  float* w = (float*)d_ws;
  size_t o = 0;
  auto alloc = [&](size_t n) { float* p = w + o; o += (n + 3) & ~(size_t)3; return p; };

  unsigned short* H  = (unsigned short*)alloc((size_t)N * D / 2);
  unsigned short* XT = (unsigned short*)alloc((size_t)N * D / 2);
  unsigned short* HF = (unsigned short*)alloc((size_t)E * D / 2);
  int*   ROW  = (int*)alloc(M);
  int*   COL  = (int*)alloc(M);
  float* EWf  = alloc(M);
  i2*    ENTA = (i2*)alloc((size_t)M * 2);
  i2*    ENTB = (i2*)alloc((size_t)M * 2);
  int*   cursE = (int*)alloc(E);    // cursE,cursN contiguous (one memset)
  int*   cursN = (int*)alloc(N);
  float* ND   = alloc(N);
  float* SCE  = alloc(E);
  int*   offE = (int*)alloc(E + 1);
  int*   offN = (int*)alloc(N + 1);
  float* WMf  = alloc(E);
  float* FCW  = alloc((size_t)IN_DIM * D);
  float* FCB  = alloc(D);
  float* CWf  = alloc((size_t)L * D * D);
  float* CBf  = alloc((size_t)L * D);
  int*   BSE  = (int*)alloc(1026);
  int*   BSN  = (int*)alloc(1026);
  int*   FLAGS = (int*)alloc(16);

  detect_kernel<<<1, 64, 0, stream>>>((const unsigned int*)x, (const unsigned int*)hei, FLAGS);

  hipMemsetAsync(cursE, 0, (size_t)(E + N) * sizeof(int), stream);
  cvt_idx_hist<<<(M + 255) / 256, 256, 0, stream>>>(hei, ew, M, ROW, COL, EWf,
                                                    cursN, cursE, FLAGS);
  cvt_f32<<<(E + 255) / 256, 256, 0, stream>>>(wM, WMf, E, FLAGS);
  cvt_f32<<<(IN_DIM * D + 255) / 256, 256, 0, stream>>>(fcw, FCW, IN_DIM * D, FLAGS);
  cvt_f32<<<1, 256, 0, stream>>>(fcb, FCB, D, FLAGS);
  cvt_f32<<<(L * D * D + 255) / 256, 256, 0, stream>>>(cw, CWf, L * D * D, FLAGS);
  cvt_f32<<<(L * D + 255) / 256, 256, 0, stream>>>(cb, CBf, L * D, FLAGS);

  int nbE = (E + 255) / 256, nbN = (N + 255) / 256;
  scan_p1<<<nbE, 256, 0, stream>>>(cursE, BSE, E);
  scan_p2<<<1, 1024, 0, stream>>>(BSE, nbE);
  scan_p3<<<nbE, 256, 0, stream>>>(cursE, BSE, offE, E);
  scan_p1<<<nbN, 256, 0, stream>>>(cursN, BSN, N);
  scan_p2<<<1, 1024, 0, stream>>>(BSN, nbN);
  scan_p3<<<nbN, 256, 0, stream>>>(cursN, BSN, offN, N);

  hipMemsetAsync(cursE, 0, (size_t)(E + N) * sizeof(int), stream);
  permfill2<<<(M + 255) / 256, 256, 0, stream>>>(ROW, COL, EWf, offE, offN,
                                                 cursE, cursN, ENTA, ENTB, M);

  degE_kernel<<<(E + 255) / 256, 256, 0, stream>>>(ENTA, offE, WMf, SCE, E);
  degN_kernel<<<(N + 255) / 256, 256, 0, stream>>>(ENTB, offN, WMf, ND, N);

  // h0 = relu(x @ fc_w + fc_b)   (unscaled)
  gemm_kernel<<<(N + 63) / 64, 256, 0, stream>>>(x, FCW, FCB, H, N, IN_DIM, FLAGS, 1, nullptr);

  int segBlkE = (E + 3) / 4, segBlkN = (N + 3) / 4;
  for (int l = 0; l < L; ++l) {
    // xt' = nd[r] * (h @ conv_w[l] + conv_b[l])
    gemm_kernel<<<(N + 63) / 64, 256, 0, stream>>>(H, CWf + (size_t)l * D * D,
                                                   CBf + (size_t)l * D, XT, N, D,
                                                   (const int*)nullptr, 0, ND);
    gather_edge2<<<segBlkE, 256, 0, stream>>>(offE, ENTA, SCE, XT, HF, E);
    gather_node2<<<segBlkN, 256, 0, stream>>>(
        offN, ENTB, ND, HF, H,
        (l == L - 1) ? d_out : (void*)H, N, (l == L - 1) ? 1 : 0);
  }
}

// Round 6
// 525.931 us; speedup vs baseline: 1.7968x; 1.0417x over previous
//
#include <hip/hip_runtime.h>
#include <hip/hip_bf16.h>
#include <stdint.h>

typedef __attribute__((ext_vector_type(4))) float f4;
typedef __attribute__((ext_vector_type(2))) float f2;
typedef __attribute__((ext_vector_type(2))) int i2;
typedef __attribute__((ext_vector_type(8))) unsigned short us8;
typedef __attribute__((ext_vector_type(4))) unsigned short us4;
typedef __attribute__((ext_vector_type(2))) unsigned short us2;
typedef __attribute__((ext_vector_type(8))) short s8b;    // MFMA A/B frag (8 bf16)
typedef __attribute__((ext_vector_type(4))) float f32x4;  // MFMA C/D frag

__device__ __forceinline__ float bf2f(unsigned short u) {
  union { unsigned int i; float f; } t; t.i = ((unsigned int)u) << 16; return t.f;
}
__device__ __forceinline__ unsigned short f2bf(float f) {
  union { float f; unsigned int i; } t; t.f = f;
  unsigned int u = t.i;
  return (unsigned short)((u + 0x7FFFu + ((u >> 16) & 1u)) >> 16);
}

// ---- dtype detection ----
__global__ void detect_kernel(const unsigned int* __restrict__ xb,
                              const unsigned int* __restrict__ ib,
                              int* __restrict__ flags) {
  if (threadIdx.x == 0) {
    int cnt = 0;
    for (int i = 0; i < 256; ++i) {
      unsigned int e = (xb[i] >> 7) & 0xffu;
      if (e >= 110u && e <= 135u) ++cnt;
    }
    flags[0] = (cnt >= 180) ? 1 : 0;
    int zc = 0;
    for (int i = 0; i < 128; ++i) if (ib[2 * i + 1] == 0u) ++zc;
    flags[1] = (zc >= 120) ? 1 : 0;
  }
}

__global__ void cvt_f32(const void* __restrict__ src, float* __restrict__ dst,
                        int n, const int* __restrict__ flags) {
  int i = blockIdx.x * 256 + threadIdx.x;
  if (i >= n) return;
  if (flags[0]) dst[i] = bf2f(((const unsigned short*)src)[i]);
  else          dst[i] = ((const float*)src)[i];
}

// ---- weight convert + transpose: dst[c*K + k] = bf16(src[off + k*C + c]) ----
__global__ void cvt_wt(const void* __restrict__ src, unsigned short* __restrict__ dst,
                       int K, int C, int off, const int* __restrict__ flags) {
  int i = blockIdx.x * 256 + threadIdx.x;
  if (i >= K * C) return;
  int c = i / K, k = i - c * K;
  int si = off + k * C + c;
  float v = flags[0] ? bf2f(((const unsigned short*)src)[si]) : ((const float*)src)[si];
  dst[i] = f2bf(v);
}

// ---- index convert + edge-weight convert + CSR count histogram (one pass) ----
__global__ void cvt_idx_hist(const void* __restrict__ hei, const void* __restrict__ ew,
                             int M, int* __restrict__ ROW, int* __restrict__ COL,
                             float* __restrict__ EWf,
                             int* __restrict__ cntN, int* __restrict__ cntE,
                             const int* __restrict__ flags) {
  int m = blockIdx.x * 256 + threadIdx.x;
  if (m >= M) return;
  int r, c;
  if (flags[1]) {
    r = (int)((const long long*)hei)[m];
    c = (int)((const long long*)hei)[M + m];
  } else {
    r = ((const int*)hei)[m];
    c = ((const int*)hei)[M + m];
  }
  ROW[m] = r; COL[m] = c;
  EWf[m] = flags[0] ? bf2f(((const unsigned short*)ew)[m]) : ((const float*)ew)[m];
  atomicAdd(cntN + r, 1);
  atomicAdd(cntE + c, 1);
}

// ---- multi-block 3-phase exclusive scan ----
__global__ __launch_bounds__(256) void scan_p1(const int* __restrict__ cnt,
                                               int* __restrict__ bsum, int n) {
  __shared__ int s[256];
  int i = blockIdx.x * 256 + threadIdx.x;
  s[threadIdx.x] = (i < n) ? cnt[i] : 0;
  __syncthreads();
  for (int st = 128; st > 0; st >>= 1) {
    if (threadIdx.x < st) s[threadIdx.x] += s[threadIdx.x + st];
    __syncthreads();
  }
  if (threadIdx.x == 0) bsum[blockIdx.x] = s[0];
}

__global__ __launch_bounds__(1024) void scan_p2(int* __restrict__ bsum, int nb) {
  __shared__ int buf[1024];
  int tid = threadIdx.x;
  int v = (tid < nb) ? bsum[tid] : 0;
  buf[tid] = v;
  __syncthreads();
  for (int s = 1; s < 1024; s <<= 1) {
    int t = (tid >= s) ? buf[tid - s] : 0;
    __syncthreads();
    buf[tid] += t;
    __syncthreads();
  }
  if (tid < nb) bsum[tid] = buf[tid] - v;
  if (tid == 0) bsum[nb] = buf[1023];
}

__global__ __launch_bounds__(256) void scan_p3(const int* __restrict__ cnt,
                                               const int* __restrict__ bsum,
                                               int* __restrict__ off, int n) {
  __shared__ int buf[256];
  int i = blockIdx.x * 256 + threadIdx.x;
  int v = (i < n) ? cnt[i] : 0;
  buf[threadIdx.x] = v;
  __syncthreads();
  for (int s = 1; s < 256; s <<= 1) {
    int t = (threadIdx.x >= s) ? buf[threadIdx.x - s] : 0;
    __syncthreads();
    buf[threadIdx.x] += t;
    __syncthreads();
  }
  if (i < n) off[i] = bsum[blockIdx.x] + buf[threadIdx.x] - v;
  if (i == 0) off[n] = bsum[gridDim.x];
}

// ---- CSR fill: 8-byte (src, ew) entries ----
__global__ void permfill2(const int* __restrict__ ROW, const int* __restrict__ COL,
                          const float* __restrict__ EWf,
                          const int* __restrict__ offE, const int* __restrict__ offN,
                          int* __restrict__ cursE, int* __restrict__ cursN,
                          i2* __restrict__ ENTA, i2* __restrict__ ENTB, int M) {
  int m = blockIdx.x * 256 + threadIdx.x;
  if (m >= M) return;
  int r = ROW[m], c = COL[m];
  int e = __float_as_int(EWf[m]);
  int p = offE[c] + atomicAdd(cursE + c, 1);
  i2 ea; ea[0] = r; ea[1] = e; ENTA[p] = ea;
  int q = offN[r] + atomicAdd(cursN + r, 1);
  i2 eb; eb[0] = c; eb[1] = e; ENTB[q] = eb;
}

// ---- degrees from CSR (no atomics) ----
__global__ void degE_kernel(const i2* __restrict__ ENTA, const int* __restrict__ offE,
                            const float* __restrict__ WMf, float* __restrict__ sc_e, int E) {
  int c = blockIdx.x * 256 + threadIdx.x;
  if (c >= E) return;
  int k0 = offE[c], k1 = offE[c + 1];
  float s = 0.f;
  for (int k = k0; k < k1; ++k) s += __int_as_float(ENTA[k][1]);
  sc_e[c] = WMf[c] / (s + 1e-8f);
}

__global__ void degN_kernel(const i2* __restrict__ ENTB, const int* __restrict__ offN,
                            const float* __restrict__ WMf, float* __restrict__ nd, int N) {
  int r = blockIdx.x * 256 + threadIdx.x;
  if (r >= N) return;
  int k0 = offN[r], k1 = offN[r + 1];
  float s = 0.f;
  for (int k = k0; k < k1; ++k) s += WMf[ENTB[k][0]];
  nd[r] = rsqrtf(s + 1e-8f);
}

// ---- MFMA GEMM: out_bf16[N,128] = rowScale?*(relu?)(A[N,K] @ W + bias) ----
// Wt[128][K] bf16 pre-transposed. A bf16 [N][K]; if useFlagsForA!=0, A dtype is
// fp32 when flags[0]==0 (the raw x input), bf16 otherwise.
__global__ __launch_bounds__(256) void gemm_mfma(
    const void* __restrict__ Aptr, const unsigned short* __restrict__ Wt,
    const float* __restrict__ bias, unsigned short* __restrict__ out,
    int Nrows, int K, const int* __restrict__ flags, int relu,
    const float* __restrict__ rowScale) {
  const int tid = threadIdx.x;
  const int wv = tid >> 6, ln = tid & 63;
  const int lr = ln & 15;            // row (A/D) or col (B/D) within 16-tile
  const int lk = (ln >> 4) << 3;     // k-offset of this lane group
  const int r0 = blockIdx.x * 64 + wv * 16;
  const int aF32 = flags ? (flags[0] ? 0 : 1) : 0;

  f32x4 acc[8];
#pragma unroll
  for (int n = 0; n < 8; ++n) acc[n] = (f32x4)0.f;

  int arow = r0 + lr;
  if (arow >= Nrows) arow = Nrows - 1;   // clamp; stores are guarded

  for (int k0 = 0; k0 < K; k0 += 32) {
    s8b a;
    if (aF32) {
      const float* ap = (const float*)Aptr + (size_t)arow * K + k0 + lk;
      f4 u0 = *reinterpret_cast<const f4*>(ap);
      f4 u1 = *reinterpret_cast<const f4*>(ap + 4);
#pragma unroll
      for (int j = 0; j < 4; ++j) {
        a[j]     = (short)f2bf(u0[j]);
        a[4 + j] = (short)f2bf(u1[j]);
      }
    } else {
      a = *reinterpret_cast<const s8b*>(
          (const unsigned short*)Aptr + (size_t)arow * K + k0 + lk);
    }
#pragma unroll
    for (int n = 0; n < 8; ++n) {
      s8b b = *reinterpret_cast<const s8b*>(Wt + (size_t)(n * 16 + lr) * K + k0 + lk);
      acc[n] = __builtin_amdgcn_mfma_f32_16x16x32_bf16(a, b, acc[n], 0, 0, 0);
    }
  }

  const int orow0 = r0 + ((ln >> 4) << 2);
#pragma unroll
  for (int n = 0; n < 8; ++n) {
    const int col = n * 16 + lr;
    const float bv = bias[col];
#pragma unroll
    for (int r = 0; r < 4; ++r) {
      int row = orow0 + r;
      if (row >= Nrows) continue;
      float s = acc[n][r] + bv;
      if (relu) s = fmaxf(s, 0.f);
      if (rowScale) s *= rowScale[row];
      out[(size_t)row * 128 + col] = f2bf(s);
    }
  }
}

// ---- gather A: HF[c,:] = sc_e[c] * sum_k ew_k * X[src_k,:] ----
__global__ __launch_bounds__(256) void gather_edge2(
    const int* __restrict__ off, const i2* __restrict__ ENT,
    const float* __restrict__ sc_e, const unsigned short* __restrict__ X,
    unsigned short* __restrict__ out, int nseg) {
  int seg = blockIdx.x * 4 + (threadIdx.x >> 6);
  if (seg >= nseg) return;
  int d = (threadIdx.x & 63) << 1;
  int k0 = off[seg], k1 = off[seg + 1];
  float a0 = 0.f, a1 = 0.f;
  int k = k0;
  for (; k + 4 <= k1; k += 4) {
    i2 e0 = ENT[k], e1 = ENT[k + 1], e2 = ENT[k + 2], e3 = ENT[k + 3];
    us2 v0 = *reinterpret_cast<const us2*>(X + (size_t)e0[0] * 128 + d);
    us2 v1 = *reinterpret_cast<const us2*>(X + (size_t)e1[0] * 128 + d);
    us2 v2 = *reinterpret_cast<const us2*>(X + (size_t)e2[0] * 128 + d);
    us2 v3 = *reinterpret_cast<const us2*>(X + (size_t)e3[0] * 128 + d);
    float c0 = __int_as_float(e0[1]), c1 = __int_as_float(e1[1]);
    float c2 = __int_as_float(e2[1]), c3 = __int_as_float(e3[1]);
    a0 += c0 * bf2f(v0[0]); a1 += c0 * bf2f(v0[1]);
    a0 += c1 * bf2f(v1[0]); a1 += c1 * bf2f(v1[1]);
    a0 += c2 * bf2f(v2[0]); a1 += c2 * bf2f(v2[1]);
    a0 += c3 * bf2f(v3[0]); a1 += c3 * bf2f(v3[1]);
  }
  for (; k < k1; ++k) {
    i2 e = ENT[k];
    us2 v = *reinterpret_cast<const us2*>(X + (size_t)e[0] * 128 + d);
    float c = __int_as_float(e[1]);
    a0 += c * bf2f(v[0]); a1 += c * bf2f(v[1]);
  }
  float sc = sc_e[seg];
  us2 o; o[0] = f2bf(sc * a0); o[1] = f2bf(sc * a1);
  *reinterpret_cast<us2*>(out + (size_t)seg * 128 + d) = o;
}

// ---- gather B + h = relu(h + nd[r]*sum) ----
__global__ __launch_bounds__(256) void gather_node2(
    const int* __restrict__ off, const i2* __restrict__ ENT,
    const float* __restrict__ nd, const unsigned short* __restrict__ HF,
    const unsigned short* __restrict__ H, void* __restrict__ out,
    int nseg, int outF32) {
  int seg = blockIdx.x * 4 + (threadIdx.x >> 6);
  if (seg >= nseg) return;
  int d = (threadIdx.x & 63) << 1;
  int k0 = off[seg], k1 = off[seg + 1];
  float a0 = 0.f, a1 = 0.f;
  int k = k0;
  for (; k + 4 <= k1; k += 4) {
    i2 e0 = ENT[k], e1 = ENT[k + 1], e2 = ENT[k + 2], e3 = ENT[k + 3];
    us2 v0 = *reinterpret_cast<const us2*>(HF + (size_t)e0[0] * 128 + d);
    us2 v1 = *reinterpret_cast<const us2*>(HF + (size_t)e1[0] * 128 + d);
    us2 v2 = *reinterpret_cast<const us2*>(HF + (size_t)e2[0] * 128 + d);
    us2 v3 = *reinterpret_cast<const us2*>(HF + (size_t)e3[0] * 128 + d);
    float c0 = __int_as_float(e0[1]), c1 = __int_as_float(e1[1]);
    float c2 = __int_as_float(e2[1]), c3 = __int_as_float(e3[1]);
    a0 += c0 * bf2f(v0[0]); a1 += c0 * bf2f(v0[1]);
    a0 += c1 * bf2f(v1[0]); a1 += c1 * bf2f(v1[1]);
    a0 += c2 * bf2f(v2[0]); a1 += c2 * bf2f(v2[1]);
    a0 += c3 * bf2f(v3[0]); a1 += c3 * bf2f(v3[1]);
  }
  for (; k < k1; ++k) {
    i2 e = ENT[k];
    us2 v = *reinterpret_cast<const us2*>(HF + (size_t)e[0] * 128 + d);
    float c = __int_as_float(e[1]);
    a0 += c * bf2f(v[0]); a1 += c * bf2f(v[1]);
  }
  float s = nd[seg];
  us2 h = *reinterpret_cast<const us2*>(H + (size_t)seg * 128 + d);
  float r0 = fmaxf(bf2f(h[0]) + s * a0, 0.f);
  float r1 = fmaxf(bf2f(h[1]) + s * a1, 0.f);
  if (outF32) {
    f2 o; o[0] = r0; o[1] = r1;
    *reinterpret_cast<f2*>((float*)out + (size_t)seg * 128 + d) = o;
  } else {
    us2 o; o[0] = f2bf(r0); o[1] = f2bf(r1);
    *reinterpret_cast<us2*>((unsigned short*)out + (size_t)seg * 128 + d) = o;
  }
}

extern "C" void kernel_launch(void* const* d_in, const int* in_sizes, int n_in,
                              void* d_out, int out_size, void* d_ws, size_t ws_size,
                              hipStream_t stream) {
  const void* x   = d_in[0];
  const void* hei = d_in[1];
  const void* wM  = d_in[2];
  const void* ew  = d_in[3];
  const void* fcw = d_in[4];
  const void* fcb = d_in[5];
  const void* cw  = d_in[6];
  const void* cb  = d_in[7];

  const int IN_DIM = 256, D = 128;
  const int N = in_sizes[0] / IN_DIM;
  const int M = in_sizes[1] / 2;
  const int E = in_sizes[2];
  const int L = in_sizes[6] / (D * D);

  float* w = (float*)d_ws;
  size_t o = 0;
  auto alloc = [&](size_t n) { float* p = w + o; o += (n + 3) & ~(size_t)3; return p; };

  unsigned short* H  = (unsigned short*)alloc((size_t)N * D / 2);
  unsigned short* XT = (unsigned short*)alloc((size_t)N * D / 2);
  unsigned short* HF = (unsigned short*)alloc((size_t)E * D / 2);
  int*   ROW  = (int*)alloc(M);
  int*   COL  = (int*)alloc(M);
  float* EWf  = alloc(M);
  i2*    ENTA = (i2*)alloc((size_t)M * 2);
  i2*    ENTB = (i2*)alloc((size_t)M * 2);
  int*   cursE = (int*)alloc(E);    // cursE,cursN contiguous (one memset)
  int*   cursN = (int*)alloc(N);
  float* ND   = alloc(N);
  float* SCE  = alloc(E);
  int*   offE = (int*)alloc(E + 1);
  int*   offN = (int*)alloc(N + 1);
  float* WMf  = alloc(E);
  unsigned short* FCWT = (unsigned short*)alloc((size_t)IN_DIM * D / 2);  // [128][256]
  float* FCB  = alloc(D);
  unsigned short* CWT = (unsigned short*)alloc((size_t)L * D * D / 2);    // [L][128][128]
  float* CBf  = alloc((size_t)L * D);
  int*   BSE  = (int*)alloc(1026);
  int*   BSN  = (int*)alloc(1026);
  int*   FLAGS = (int*)alloc(16);

  detect_kernel<<<1, 64, 0, stream>>>((const unsigned int*)x, (const unsigned int*)hei, FLAGS);

  hipMemsetAsync(cursE, 0, (size_t)(E + N) * sizeof(int), stream);
  cvt_idx_hist<<<(M + 255) / 256, 256, 0, stream>>>(hei, ew, M, ROW, COL, EWf,
                                                    cursN, cursE, FLAGS);
  cvt_f32<<<(E + 255) / 256, 256, 0, stream>>>(wM, WMf, E, FLAGS);
  cvt_wt<<<(IN_DIM * D + 255) / 256, 256, 0, stream>>>(fcw, FCWT, IN_DIM, D, 0, FLAGS);
  cvt_f32<<<1, 256, 0, stream>>>(fcb, FCB, D, FLAGS);
  for (int l = 0; l < L; ++l)
    cvt_wt<<<(D * D + 255) / 256, 256, 0, stream>>>(cw, CWT + (size_t)l * D * D,
                                                    D, D, l * D * D, FLAGS);
  cvt_f32<<<(L * D + 255) / 256, 256, 0, stream>>>(cb, CBf, L * D, FLAGS);

  int nbE = (E + 255) / 256, nbN = (N + 255) / 256;
  scan_p1<<<nbE, 256, 0, stream>>>(cursE, BSE, E);
  scan_p2<<<1, 1024, 0, stream>>>(BSE, nbE);
  scan_p3<<<nbE, 256, 0, stream>>>(cursE, BSE, offE, E);
  scan_p1<<<nbN, 256, 0, stream>>>(cursN, BSN, N);
  scan_p2<<<1, 1024, 0, stream>>>(BSN, nbN);
  scan_p3<<<nbN, 256, 0, stream>>>(cursN, BSN, offN, N);

  hipMemsetAsync(cursE, 0, (size_t)(E + N) * sizeof(int), stream);
  permfill2<<<(M + 255) / 256, 256, 0, stream>>>(ROW, COL, EWf, offE, offN,
                                                 cursE, cursN, ENTA, ENTB, M);

  degE_kernel<<<(E + 255) / 256, 256, 0, stream>>>(ENTA, offE, WMf, SCE, E);
  degN_kernel<<<(N + 255) / 256, 256, 0, stream>>>(ENTB, offN, WMf, ND, N);

  // h0 = relu(x @ fc_w + fc_b); A dtype resolved inside via FLAGS
  gemm_mfma<<<(N + 63) / 64, 256, 0, stream>>>(x, FCWT, FCB, H, N, IN_DIM,
                                               FLAGS, 1, nullptr);

  int segBlkE = (E + 3) / 4, segBlkN = (N + 3) / 4;
  for (int l = 0; l < L; ++l) {
    // xt' = nd[r] * (h @ conv_w[l] + conv_b[l])
    gemm_mfma<<<(N + 63) / 64, 256, 0, stream>>>(H, CWT + (size_t)l * D * D,
                                                 CBf + (size_t)l * D, XT, N, D,
                                                 (const int*)nullptr, 0, ND);
    gather_edge2<<<segBlkE, 256, 0, stream>>>(offE, ENTA, SCE, XT, HF, E);
    gather_node2<<<segBlkN, 256, 0, stream>>>(
        offN, ENTB, ND, HF, H,
        (l == L - 1) ? d_out : (void*)H, N, (l == L - 1) ? 1 : 0);
  }
}

// Round 7
// 449.833 us; speedup vs baseline: 2.1008x; 1.1692x over previous
//
#include <hip/hip_runtime.h>
#include <hip/hip_bf16.h>
#include <stdint.h>

typedef __attribute__((ext_vector_type(4))) float f4;
typedef __attribute__((ext_vector_type(2))) float f2;
typedef __attribute__((ext_vector_type(2))) int i2;
typedef __attribute__((ext_vector_type(8))) unsigned short us8;
typedef __attribute__((ext_vector_type(4))) unsigned short us4;
typedef __attribute__((ext_vector_type(2))) unsigned short us2;
typedef __attribute__((ext_vector_type(8))) short s8b;    // MFMA A/B frag (8 bf16)
typedef __attribute__((ext_vector_type(4))) float f32x4;  // MFMA C/D frag

#define CW_SHIFT 7            // 128 cols per bucket
#define CH 2048               // edges per block in bin phases

__device__ __forceinline__ float bf2f(unsigned short u) {
  union { unsigned int i; float f; } t; t.i = ((unsigned int)u) << 16; return t.f;
}
__device__ __forceinline__ unsigned short f2bf(float f) {
  union { float f; unsigned int i; } t; t.f = f;
  unsigned int u = t.i;
  return (unsigned short)((u + 0x7FFFu + ((u >> 16) & 1u)) >> 16);
}

// ---- dtype detection ----
__global__ void detect_kernel(const unsigned int* __restrict__ xb,
                              const unsigned int* __restrict__ ib,
                              int* __restrict__ flags) {
  if (threadIdx.x == 0) {
    int cnt = 0;
    for (int i = 0; i < 256; ++i) {
      unsigned int e = (xb[i] >> 7) & 0xffu;
      if (e >= 110u && e <= 135u) ++cnt;
    }
    flags[0] = (cnt >= 180) ? 1 : 0;
    int zc = 0;
    for (int i = 0; i < 128; ++i) if (ib[2 * i + 1] == 0u) ++zc;
    flags[1] = (zc >= 120) ? 1 : 0;
  }
}

__global__ void cvt_f32(const void* __restrict__ src, float* __restrict__ dst,
                        int n, const int* __restrict__ flags) {
  int i = blockIdx.x * 256 + threadIdx.x;
  if (i >= n) return;
  if (flags[0]) dst[i] = bf2f(((const unsigned short*)src)[i]);
  else          dst[i] = ((const float*)src)[i];
}

// ---- weight convert + transpose: dst[c*K + k] = bf16(src[off + k*C + c]) ----
__global__ void cvt_wt(const void* __restrict__ src, unsigned short* __restrict__ dst,
                       int K, int C, int off, const int* __restrict__ flags) {
  int i = blockIdx.x * 256 + threadIdx.x;
  if (i >= K * C) return;
  int c = i / K, k = i - c * K;
  int si = off + k * C + c;
  float v = flags[0] ? bf2f(((const unsigned short*)src)[si]) : ((const float*)src)[si];
  dst[i] = f2bf(v);
}

// ---- phase 1: convert indices/edge-weights + per-(block,bucket) histograms ----
// cntA layout: [bucket][block]  (bucket-major for the scan)
__global__ __launch_bounds__(256) void cvt_bin_count(
    const void* __restrict__ hei, const void* __restrict__ ew, int M,
    int* __restrict__ ROW, int* __restrict__ COL, float* __restrict__ EWf,
    int* __restrict__ cntA, int* __restrict__ cntB,
    int nbE, int nbN, int nblk, const int* __restrict__ flags) {
  __shared__ int hA[512];
  __shared__ int hB[512];
  const int tid = threadIdx.x, blk = blockIdx.x;
  for (int b = tid; b < 512; b += 256) { hA[b] = 0; hB[b] = 0; }
  __syncthreads();
  const int i64 = flags[1], f16 = flags[0];
#pragma unroll
  for (int i = 0; i < CH / 256; ++i) {
    int m = blk * CH + i * 256 + tid;
    if (m >= M) break;
    int r, c;
    if (i64) {
      r = (int)((const long long*)hei)[m];
      c = (int)((const long long*)hei)[M + m];
    } else {
      r = ((const int*)hei)[m];
      c = ((const int*)hei)[M + m];
    }
    ROW[m] = r; COL[m] = c;
    EWf[m] = f16 ? bf2f(((const unsigned short*)ew)[m]) : ((const float*)ew)[m];
    atomicAdd(&hA[c >> CW_SHIFT], 1);
    atomicAdd(&hB[r >> CW_SHIFT], 1);
  }
  __syncthreads();
  for (int b = tid; b < nbE; b += 256) cntA[b * nblk + blk] = hA[b];
  for (int b = tid; b < nbN; b += 256) cntB[b * nblk + blk] = hB[b];
}

// ---- scanA: per-bucket exclusive scan (in place) over nblk block counts ----
__global__ __launch_bounds__(512) void scanA(int* __restrict__ cnt,
                                             int* __restrict__ btot, int nblk) {
  __shared__ int sc[512];
  const int tid = threadIdx.x, b = blockIdx.x;
  int v = (tid < nblk) ? cnt[b * nblk + tid] : 0;
  sc[tid] = v;
  __syncthreads();
  for (int s = 1; s < 512; s <<= 1) {
    int t = (tid >= s) ? sc[tid - s] : 0;
    __syncthreads();
    sc[tid] += t;
    __syncthreads();
  }
  if (tid < nblk) cnt[b * nblk + tid] = sc[tid] - v;
  if (tid == 511) btot[b] = sc[511];
}

// ---- scanB: single-block exclusive scan of bucket totals -> bbase[nb+1] ----
__global__ __launch_bounds__(512) void scanB(const int* __restrict__ btot,
                                             int* __restrict__ bbase, int nb) {
  __shared__ int sc[512];
  const int tid = threadIdx.x;
  int v = (tid < nb) ? btot[tid] : 0;
  sc[tid] = v;
  __syncthreads();
  for (int s = 1; s < 512; s <<= 1) {
    int t = (tid >= s) ? sc[tid - s] : 0;
    __syncthreads();
    sc[tid] += t;
    __syncthreads();
  }
  if (tid < nb) bbase[tid] = sc[tid] - v;
  if (tid == 511) bbase[nb] = sc[511];
}

// ---- phase 2: scatter edges into bucket-major binned arrays (block-owned chunks) ----
__global__ __launch_bounds__(256) void binscatter(
    const int* __restrict__ ROW, const int* __restrict__ COL,
    const float* __restrict__ EWf, int M,
    const int* __restrict__ cntA, const int* __restrict__ bbaseA,
    const int* __restrict__ cntB, const int* __restrict__ bbaseB,
    int* __restrict__ KEYA, i2* __restrict__ PAYA,
    int* __restrict__ KEYB, i2* __restrict__ PAYB,
    int nbE, int nbN, int nblk) {
  __shared__ int baseA[512];
  __shared__ int baseB[512];
  const int tid = threadIdx.x, blk = blockIdx.x;
  for (int b = tid; b < nbE; b += 256) baseA[b] = bbaseA[b] + cntA[b * nblk + blk];
  for (int b = tid; b < nbN; b += 256) baseB[b] = bbaseB[b] + cntB[b * nblk + blk];
  __syncthreads();
#pragma unroll
  for (int i = 0; i < CH / 256; ++i) {
    int m = blk * CH + i * 256 + tid;
    if (m >= M) break;
    int r = ROW[m], c = COL[m];
    int e = __float_as_int(EWf[m]);
    int pA = atomicAdd(&baseA[c >> CW_SHIFT], 1);
    KEYA[pA] = c;
    i2 ea; ea[0] = r; ea[1] = e; PAYA[pA] = ea;
    int pB = atomicAdd(&baseB[r >> CW_SHIFT], 1);
    KEYB[pB] = r;
    i2 eb; eb[0] = c; eb[1] = e; PAYB[pB] = eb;
  }
}

// ---- phase 3: per-bucket finalize -> CSR entries + segment offsets ----
__global__ __launch_bounds__(256) void finalize(
    const int* __restrict__ KEY, const i2* __restrict__ PAY,
    const int* __restrict__ bbase, i2* __restrict__ ENT,
    int* __restrict__ off, int nseg) {
  __shared__ int cnt[128];
  __shared__ int sc[128];
  __shared__ int cur[128];
  const int tid = threadIdx.x, b = blockIdx.x;
  const int bs = bbase[b], be = bbase[b + 1];
  const int cb = b << CW_SHIFT;
  const int cw = min(128, nseg - cb);
  if (tid < 128) cnt[tid] = 0;
  __syncthreads();
  for (int k = bs + tid; k < be; k += 256) atomicAdd(&cnt[KEY[k] - cb], 1);
  __syncthreads();
  // exclusive scan of cnt[0..127]
  if (tid < 128) sc[tid] = cnt[tid];
  __syncthreads();
  for (int s = 1; s < 128; s <<= 1) {
    int t = (tid < 128 && tid >= s) ? sc[tid - s] : 0;
    __syncthreads();
    if (tid < 128) sc[tid] += t;
    __syncthreads();
  }
  if (tid < 128) {
    int start = bs + sc[tid] - cnt[tid];
    cur[tid] = start;
    if (tid < cw) off[cb + tid] = start;
  }
  if (b == gridDim.x - 1 && tid == 0) off[nseg] = be;
  __syncthreads();
  for (int k = bs + tid; k < be; k += 256) {
    int c = KEY[k] - cb;
    int pos = atomicAdd(&cur[c], 1);
    ENT[pos] = PAY[k];
  }
}

// ---- degrees from CSR (no atomics) ----
__global__ void degE_kernel(const i2* __restrict__ ENTA, const int* __restrict__ offE,
                            const float* __restrict__ WMf, float* __restrict__ sc_e, int E) {
  int c = blockIdx.x * 256 + threadIdx.x;
  if (c >= E) return;
  int k0 = offE[c], k1 = offE[c + 1];
  float s = 0.f;
  for (int k = k0; k < k1; ++k) s += __int_as_float(ENTA[k][1]);
  sc_e[c] = WMf[c] / (s + 1e-8f);
}

__global__ void degN_kernel(const i2* __restrict__ ENTB, const int* __restrict__ offN,
                            const float* __restrict__ WMf, float* __restrict__ nd, int N) {
  int r = blockIdx.x * 256 + threadIdx.x;
  if (r >= N) return;
  int k0 = offN[r], k1 = offN[r + 1];
  float s = 0.f;
  for (int k = k0; k < k1; ++k) s += WMf[ENTB[k][0]];
  nd[r] = rsqrtf(s + 1e-8f);
}

// ---- MFMA GEMM: out_bf16[N,128] = rowScale?*(relu?)(A[N,K] @ W + bias) ----
__global__ __launch_bounds__(256) void gemm_mfma(
    const void* __restrict__ Aptr, const unsigned short* __restrict__ Wt,
    const float* __restrict__ bias, unsigned short* __restrict__ out,
    int Nrows, int K, const int* __restrict__ flags, int relu,
    const float* __restrict__ rowScale) {
  const int tid = threadIdx.x;
  const int wv = tid >> 6, ln = tid & 63;
  const int lr = ln & 15;
  const int lk = (ln >> 4) << 3;
  const int r0 = blockIdx.x * 64 + wv * 16;
  const int aF32 = flags ? (flags[0] ? 0 : 1) : 0;

  f32x4 acc[8];
#pragma unroll
  for (int n = 0; n < 8; ++n) acc[n] = (f32x4)0.f;

  int arow = r0 + lr;
  if (arow >= Nrows) arow = Nrows - 1;

  for (int k0 = 0; k0 < K; k0 += 32) {
    s8b a;
    if (aF32) {
      const float* ap = (const float*)Aptr + (size_t)arow * K + k0 + lk;
      f4 u0 = *reinterpret_cast<const f4*>(ap);
      f4 u1 = *reinterpret_cast<const f4*>(ap + 4);
#pragma unroll
      for (int j = 0; j < 4; ++j) {
        a[j]     = (short)f2bf(u0[j]);
        a[4 + j] = (short)f2bf(u1[j]);
      }
    } else {
      a = *reinterpret_cast<const s8b*>(
          (const unsigned short*)Aptr + (size_t)arow * K + k0 + lk);
    }
#pragma unroll
    for (int n = 0; n < 8; ++n) {
      s8b b = *reinterpret_cast<const s8b*>(Wt + (size_t)(n * 16 + lr) * K + k0 + lk);
      acc[n] = __builtin_amdgcn_mfma_f32_16x16x32_bf16(a, b, acc[n], 0, 0, 0);
    }
  }

  const int orow0 = r0 + ((ln >> 4) << 2);
#pragma unroll
  for (int n = 0; n < 8; ++n) {
    const int col = n * 16 + lr;
    const float bv = bias[col];
#pragma unroll
    for (int r = 0; r < 4; ++r) {
      int row = orow0 + r;
      if (row >= Nrows) continue;
      float s = acc[n][r] + bv;
      if (relu) s = fmaxf(s, 0.f);
      if (rowScale) s *= rowScale[row];
      out[(size_t)row * 128 + col] = f2bf(s);
    }
  }
}

// ---- gather A: HF[c,:] = sc_e[c] * sum_k ew_k * X[src_k,:] ----
__global__ __launch_bounds__(256) void gather_edge2(
    const int* __restrict__ off, const i2* __restrict__ ENT,
    const float* __restrict__ sc_e, const unsigned short* __restrict__ X,
    unsigned short* __restrict__ out, int nseg) {
  int seg = blockIdx.x * 4 + (threadIdx.x >> 6);
  if (seg >= nseg) return;
  int d = (threadIdx.x & 63) << 1;
  int k0 = off[seg], k1 = off[seg + 1];
  float a0 = 0.f, a1 = 0.f;
  int k = k0;
  for (; k + 4 <= k1; k += 4) {
    i2 e0 = ENT[k], e1 = ENT[k + 1], e2 = ENT[k + 2], e3 = ENT[k + 3];
    us2 v0 = *reinterpret_cast<const us2*>(X + (size_t)e0[0] * 128 + d);
    us2 v1 = *reinterpret_cast<const us2*>(X + (size_t)e1[0] * 128 + d);
    us2 v2 = *reinterpret_cast<const us2*>(X + (size_t)e2[0] * 128 + d);
    us2 v3 = *reinterpret_cast<const us2*>(X + (size_t)e3[0] * 128 + d);
    float c0 = __int_as_float(e0[1]), c1 = __int_as_float(e1[1]);
    float c2 = __int_as_float(e2[1]), c3 = __int_as_float(e3[1]);
    a0 += c0 * bf2f(v0[0]); a1 += c0 * bf2f(v0[1]);
    a0 += c1 * bf2f(v1[0]); a1 += c1 * bf2f(v1[1]);
    a0 += c2 * bf2f(v2[0]); a1 += c2 * bf2f(v2[1]);
    a0 += c3 * bf2f(v3[0]); a1 += c3 * bf2f(v3[1]);
  }
  for (; k < k1; ++k) {
    i2 e = ENT[k];
    us2 v = *reinterpret_cast<const us2*>(X + (size_t)e[0] * 128 + d);
    float c = __int_as_float(e[1]);
    a0 += c * bf2f(v[0]); a1 += c * bf2f(v[1]);
  }
  float sc = sc_e[seg];
  us2 o; o[0] = f2bf(sc * a0); o[1] = f2bf(sc * a1);
  *reinterpret_cast<us2*>(out + (size_t)seg * 128 + d) = o;
}

// ---- gather B + h = relu(h + nd[r]*sum) ----
__global__ __launch_bounds__(256) void gather_node2(
    const int* __restrict__ off, const i2* __restrict__ ENT,
    const float* __restrict__ nd, const unsigned short* __restrict__ HF,
    const unsigned short* __restrict__ H, void* __restrict__ out,
    int nseg, int outF32) {
  int seg = blockIdx.x * 4 + (threadIdx.x >> 6);
  if (seg >= nseg) return;
  int d = (threadIdx.x & 63) << 1;
  int k0 = off[seg], k1 = off[seg + 1];
  float a0 = 0.f, a1 = 0.f;
  int k = k0;
  for (; k + 4 <= k1; k += 4) {
    i2 e0 = ENT[k], e1 = ENT[k + 1], e2 = ENT[k + 2], e3 = ENT[k + 3];
    us2 v0 = *reinterpret_cast<const us2*>(HF + (size_t)e0[0] * 128 + d);
    us2 v1 = *reinterpret_cast<const us2*>(HF + (size_t)e1[0] * 128 + d);
    us2 v2 = *reinterpret_cast<const us2*>(HF + (size_t)e2[0] * 128 + d);
    us2 v3 = *reinterpret_cast<const us2*>(HF + (size_t)e3[0] * 128 + d);
    float c0 = __int_as_float(e0[1]), c1 = __int_as_float(e1[1]);
    float c2 = __int_as_float(e2[1]), c3 = __int_as_float(e3[1]);
    a0 += c0 * bf2f(v0[0]); a1 += c0 * bf2f(v0[1]);
    a0 += c1 * bf2f(v1[0]); a1 += c1 * bf2f(v1[1]);
    a0 += c2 * bf2f(v2[0]); a1 += c2 * bf2f(v2[1]);
    a0 += c3 * bf2f(v3[0]); a1 += c3 * bf2f(v3[1]);
  }
  for (; k < k1; ++k) {
    i2 e = ENT[k];
    us2 v = *reinterpret_cast<const us2*>(HF + (size_t)e[0] * 128 + d);
    float c = __int_as_float(e[1]);
    a0 += c * bf2f(v[0]); a1 += c * bf2f(v[1]);
  }
  float s = nd[seg];
  us2 h = *reinterpret_cast<const us2*>(H + (size_t)seg * 128 + d);
  float r0 = fmaxf(bf2f(h[0]) + s * a0, 0.f);
  float r1 = fmaxf(bf2f(h[1]) + s * a1, 0.f);
  if (outF32) {
    f2 o; o[0] = r0; o[1] = r1;
    *reinterpret_cast<f2*>((float*)out + (size_t)seg * 128 + d) = o;
  } else {
    us2 o; o[0] = f2bf(r0); o[1] = f2bf(r1);
    *reinterpret_cast<us2*>((unsigned short*)out + (size_t)seg * 128 + d) = o;
  }
}

extern "C" void kernel_launch(void* const* d_in, const int* in_sizes, int n_in,
                              void* d_out, int out_size, void* d_ws, size_t ws_size,
                              hipStream_t stream) {
  const void* x   = d_in[0];
  const void* hei = d_in[1];
  const void* wM  = d_in[2];
  const void* ew  = d_in[3];
  const void* fcw = d_in[4];
  const void* fcb = d_in[5];
  const void* cw  = d_in[6];
  const void* cb  = d_in[7];

  const int IN_DIM = 256, D = 128;
  const int N = in_sizes[0] / IN_DIM;
  const int M = in_sizes[1] / 2;
  const int E = in_sizes[2];
  const int L = in_sizes[6] / (D * D);

  const int nbE = (E + 127) >> CW_SHIFT;   // 391 for E=50000
  const int nbN = (N + 127) >> CW_SHIFT;
  const int nblk = (M + CH - 1) / CH;      // 313 for M=640000

  float* w = (float*)d_ws;
  size_t o = 0;
  auto alloc = [&](size_t n) { float* p = w + o; o += (n + 3) & ~(size_t)3; return p; };

  // R region: XT+HF later; BIN arrays now (both <= region size, disjoint in time)
  float* R = alloc((size_t)(N + E) * D / 2);       // (N+E)*64 floats = 25.6MB
  unsigned short* XT = (unsigned short*)R;
  unsigned short* HF = XT + (size_t)N * D;
  int* KEYA = (int*)R;
  i2*  PAYA = (i2*)(KEYA + M);
  int* KEYB = (int*)(PAYA + M);
  i2*  PAYB = (i2*)(KEYB + M);

  unsigned short* H  = (unsigned short*)alloc((size_t)N * D / 2);
  int*   ROW  = (int*)alloc(M);
  int*   COL  = (int*)alloc(M);
  float* EWf  = alloc(M);
  i2*    ENTA = (i2*)alloc((size_t)M * 2);
  i2*    ENTB = (i2*)alloc((size_t)M * 2);
  int*   cntA = (int*)alloc((size_t)nbE * nblk);
  int*   cntB = (int*)alloc((size_t)nbN * nblk);
  int*   btotA = (int*)alloc(nbE + 2);
  int*   btotB = (int*)alloc(nbN + 2);
  int*   bbaseA = (int*)alloc(nbE + 2);
  int*   bbaseB = (int*)alloc(nbN + 2);
  float* ND   = alloc(N);
  float* SCE  = alloc(E);
  int*   offE = (int*)alloc(E + 1);
  int*   offN = (int*)alloc(N + 1);
  float* WMf  = alloc(E);
  unsigned short* FCWT = (unsigned short*)alloc((size_t)IN_DIM * D / 2);
  float* FCB  = alloc(D);
  unsigned short* CWT = (unsigned short*)alloc((size_t)L * D * D / 2);
  float* CBf  = alloc((size_t)L * D);
  int*   FLAGS = (int*)alloc(16);

  detect_kernel<<<1, 64, 0, stream>>>((const unsigned int*)x, (const unsigned int*)hei, FLAGS);

  // phase 1: convert + per-(block,bucket) counts
  cvt_bin_count<<<nblk, 256, 0, stream>>>(hei, ew, M, ROW, COL, EWf,
                                          cntA, cntB, nbE, nbN, nblk, FLAGS);
  cvt_f32<<<(E + 255) / 256, 256, 0, stream>>>(wM, WMf, E, FLAGS);
  cvt_wt<<<(IN_DIM * D + 255) / 256, 256, 0, stream>>>(fcw, FCWT, IN_DIM, D, 0, FLAGS);
  cvt_f32<<<1, 256, 0, stream>>>(fcb, FCB, D, FLAGS);
  for (int l = 0; l < L; ++l)
    cvt_wt<<<(D * D + 255) / 256, 256, 0, stream>>>(cw, CWT + (size_t)l * D * D,
                                                    D, D, l * D * D, FLAGS);
  cvt_f32<<<(L * D + 255) / 256, 256, 0, stream>>>(cb, CBf, L * D, FLAGS);

  // scans
  scanA<<<nbE, 512, 0, stream>>>(cntA, btotA, nblk);
  scanA<<<nbN, 512, 0, stream>>>(cntB, btotB, nblk);
  scanB<<<1, 512, 0, stream>>>(btotA, bbaseA, nbE);
  scanB<<<1, 512, 0, stream>>>(btotB, bbaseB, nbN);

  // phase 2: binned scatter (streaming, block-owned chunks)
  binscatter<<<nblk, 256, 0, stream>>>(ROW, COL, EWf, M, cntA, bbaseA, cntB, bbaseB,
                                       KEYA, PAYA, KEYB, PAYB, nbE, nbN, nblk);

  // phase 3: per-bucket finalize -> ENT + off
  finalize<<<nbE, 256, 0, stream>>>(KEYA, PAYA, bbaseA, ENTA, offE, E);
  finalize<<<nbN, 256, 0, stream>>>(KEYB, PAYB, bbaseB, ENTB, offN, N);

  degE_kernel<<<(E + 255) / 256, 256, 0, stream>>>(ENTA, offE, WMf, SCE, E);
  degN_kernel<<<(N + 255) / 256, 256, 0, stream>>>(ENTB, offN, WMf, ND, N);

  // h0 = relu(x @ fc_w + fc_b); A dtype resolved inside via FLAGS
  gemm_mfma<<<(N + 63) / 64, 256, 0, stream>>>(x, FCWT, FCB, H, N, IN_DIM,
                                               FLAGS, 1, nullptr);

  int segBlkE = (E + 3) / 4, segBlkN = (N + 3) / 4;
  for (int l = 0; l < L; ++l) {
    // xt' = nd[r] * (h @ conv_w[l] + conv_b[l])   (XT aliases R; BINs are dead now)
    gemm_mfma<<<(N + 63) / 64, 256, 0, stream>>>(H, CWT + (size_t)l * D * D,
                                                 CBf + (size_t)l * D, XT, N, D,
                                                 (const int*)nullptr, 0, ND);
    gather_edge2<<<segBlkE, 256, 0, stream>>>(offE, ENTA, SCE, XT, HF, E);
    gather_node2<<<segBlkN, 256, 0, stream>>>(
        offN, ENTB, ND, HF, H,
        (l == L - 1) ? d_out : (void*)H, N, (l == L - 1) ? 1 : 0);
  }
}

// Round 8
// 418.939 us; speedup vs baseline: 2.2557x; 1.0737x over previous
//
#include <hip/hip_runtime.h>
#include <hip/hip_bf16.h>
#include <stdint.h>

typedef __attribute__((ext_vector_type(4))) float f4;
typedef __attribute__((ext_vector_type(2))) float f2;
typedef __attribute__((ext_vector_type(2))) int i2;
typedef __attribute__((ext_vector_type(8))) unsigned short us8;
typedef __attribute__((ext_vector_type(4))) unsigned short us4;
typedef __attribute__((ext_vector_type(2))) unsigned short us2;
typedef __attribute__((ext_vector_type(8))) short s8b;    // MFMA A/B frag (8 bf16)
typedef __attribute__((ext_vector_type(4))) float f32x4;  // MFMA C/D frag

#define CW_SHIFT 7            // 128 cols per bucket
#define CH 2048               // edges per block in bin phases

__device__ __forceinline__ float bf2f(unsigned short u) {
  union { unsigned int i; float f; } t; t.i = ((unsigned int)u) << 16; return t.f;
}
__device__ __forceinline__ unsigned short f2bf(float f) {
  union { float f; unsigned int i; } t; t.f = f;
  unsigned int u = t.i;
  return (unsigned short)((u + 0x7FFFu + ((u >> 16) & 1u)) >> 16);
}

// ---- dtype detection ----
__global__ void detect_kernel(const unsigned int* __restrict__ xb,
                              const unsigned int* __restrict__ ib,
                              int* __restrict__ flags) {
  if (threadIdx.x == 0) {
    int cnt = 0;
    for (int i = 0; i < 256; ++i) {
      unsigned int e = (xb[i] >> 7) & 0xffu;
      if (e >= 110u && e <= 135u) ++cnt;
    }
    flags[0] = (cnt >= 180) ? 1 : 0;
    int zc = 0;
    for (int i = 0; i < 128; ++i) if (ib[2 * i + 1] == 0u) ++zc;
    flags[1] = (zc >= 120) ? 1 : 0;
  }
}

__global__ void cvt_f32(const void* __restrict__ src, float* __restrict__ dst,
                        int n, const int* __restrict__ flags) {
  int i = blockIdx.x * 256 + threadIdx.x;
  if (i >= n) return;
  if (flags[0]) dst[i] = bf2f(((const unsigned short*)src)[i]);
  else          dst[i] = ((const float*)src)[i];
}

// ---- weight convert + transpose: dst[c*K + k] = bf16(src[off + k*C + c]) ----
__global__ void cvt_wt(const void* __restrict__ src, unsigned short* __restrict__ dst,
                       int K, int C, int off, const int* __restrict__ flags) {
  int i = blockIdx.x * 256 + threadIdx.x;
  if (i >= K * C) return;
  int c = i / K, k = i - c * K;
  int si = off + k * C + c;
  float v = flags[0] ? bf2f(((const unsigned short*)src)[si]) : ((const float*)src)[si];
  dst[i] = f2bf(v);
}

// ---- phase 1: convert indices/edge-weights + per-(block,bucket) histograms ----
__global__ __launch_bounds__(256) void cvt_bin_count(
    const void* __restrict__ hei, const void* __restrict__ ew, int M,
    int* __restrict__ ROW, int* __restrict__ COL, float* __restrict__ EWf,
    int* __restrict__ cntA, int* __restrict__ cntB,
    int nbE, int nbN, int nblk, const int* __restrict__ flags) {
  __shared__ int hA[512];
  __shared__ int hB[512];
  const int tid = threadIdx.x, blk = blockIdx.x;
  for (int b = tid; b < 512; b += 256) { hA[b] = 0; hB[b] = 0; }
  __syncthreads();
  const int i64 = flags[1], f16 = flags[0];
#pragma unroll
  for (int i = 0; i < CH / 256; ++i) {
    int m = blk * CH + i * 256 + tid;
    if (m >= M) break;
    int r, c;
    if (i64) {
      r = (int)((const long long*)hei)[m];
      c = (int)((const long long*)hei)[M + m];
    } else {
      r = ((const int*)hei)[m];
      c = ((const int*)hei)[M + m];
    }
    ROW[m] = r; COL[m] = c;
    EWf[m] = f16 ? bf2f(((const unsigned short*)ew)[m]) : ((const float*)ew)[m];
    atomicAdd(&hA[c >> CW_SHIFT], 1);
    atomicAdd(&hB[r >> CW_SHIFT], 1);
  }
  __syncthreads();
  for (int b = tid; b < nbE; b += 256) cntA[b * nblk + blk] = hA[b];
  for (int b = tid; b < nbN; b += 256) cntB[b * nblk + blk] = hB[b];
}

// ---- scanA: per-bucket exclusive scan (in place) over nblk block counts ----
__global__ __launch_bounds__(512) void scanA(int* __restrict__ cnt,
                                             int* __restrict__ btot, int nblk) {
  __shared__ int sc[512];
  const int tid = threadIdx.x, b = blockIdx.x;
  int v = (tid < nblk) ? cnt[b * nblk + tid] : 0;
  sc[tid] = v;
  __syncthreads();
  for (int s = 1; s < 512; s <<= 1) {
    int t = (tid >= s) ? sc[tid - s] : 0;
    __syncthreads();
    sc[tid] += t;
    __syncthreads();
  }
  if (tid < nblk) cnt[b * nblk + tid] = sc[tid] - v;
  if (tid == 511) btot[b] = sc[511];
}

// ---- scanB: single-block exclusive scan of bucket totals -> bbase[nb+1] ----
__global__ __launch_bounds__(512) void scanB(const int* __restrict__ btot,
                                             int* __restrict__ bbase, int nb) {
  __shared__ int sc[512];
  const int tid = threadIdx.x;
  int v = (tid < nb) ? btot[tid] : 0;
  sc[tid] = v;
  __syncthreads();
  for (int s = 1; s < 512; s <<= 1) {
    int t = (tid >= s) ? sc[tid - s] : 0;
    __syncthreads();
    sc[tid] += t;
    __syncthreads();
  }
  if (tid < nb) bbase[tid] = sc[tid] - v;
  if (tid == 511) bbase[nb] = sc[511];
}

// ---- phase 2: scatter edges into bucket-major binned arrays ----
__global__ __launch_bounds__(256) void binscatter(
    const int* __restrict__ ROW, const int* __restrict__ COL,
    const float* __restrict__ EWf, int M,
    const int* __restrict__ cntA, const int* __restrict__ bbaseA,
    const int* __restrict__ cntB, const int* __restrict__ bbaseB,
    int* __restrict__ KEYA, i2* __restrict__ PAYA,
    int* __restrict__ KEYB, i2* __restrict__ PAYB,
    int nbE, int nbN, int nblk) {
  __shared__ int baseA[512];
  __shared__ int baseB[512];
  const int tid = threadIdx.x, blk = blockIdx.x;
  for (int b = tid; b < nbE; b += 256) baseA[b] = bbaseA[b] + cntA[b * nblk + blk];
  for (int b = tid; b < nbN; b += 256) baseB[b] = bbaseB[b] + cntB[b * nblk + blk];
  __syncthreads();
#pragma unroll
  for (int i = 0; i < CH / 256; ++i) {
    int m = blk * CH + i * 256 + tid;
    if (m >= M) break;
    int r = ROW[m], c = COL[m];
    int e = __float_as_int(EWf[m]);
    int pA = atomicAdd(&baseA[c >> CW_SHIFT], 1);
    KEYA[pA] = c;
    i2 ea; ea[0] = r; ea[1] = e; PAYA[pA] = ea;
    int pB = atomicAdd(&baseB[r >> CW_SHIFT], 1);
    KEYB[pB] = r;
    i2 eb; eb[0] = c; eb[1] = e; PAYB[pB] = eb;
  }
}

// ---- phase 3: per-bucket finalize -> CSR entries + segment offsets ----
__global__ __launch_bounds__(256) void finalize(
    const int* __restrict__ KEY, const i2* __restrict__ PAY,
    const int* __restrict__ bbase, i2* __restrict__ ENT,
    int* __restrict__ off, int nseg) {
  __shared__ int cnt[128];
  __shared__ int sc[128];
  __shared__ int cur[128];
  const int tid = threadIdx.x, b = blockIdx.x;
  const int bs = bbase[b], be = bbase[b + 1];
  const int cb = b << CW_SHIFT;
  const int cw = min(128, nseg - cb);
  if (tid < 128) cnt[tid] = 0;
  __syncthreads();
  for (int k = bs + tid; k < be; k += 256) atomicAdd(&cnt[KEY[k] - cb], 1);
  __syncthreads();
  if (tid < 128) sc[tid] = cnt[tid];
  __syncthreads();
  for (int s = 1; s < 128; s <<= 1) {
    int t = (tid < 128 && tid >= s) ? sc[tid - s] : 0;
    __syncthreads();
    if (tid < 128) sc[tid] += t;
    __syncthreads();
  }
  if (tid < 128) {
    int start = bs + sc[tid] - cnt[tid];
    cur[tid] = start;
    if (tid < cw) off[cb + tid] = start;
  }
  if (b == gridDim.x - 1 && tid == 0) off[nseg] = be;
  __syncthreads();
  for (int k = bs + tid; k < be; k += 256) {
    int c = KEY[k] - cb;
    int pos = atomicAdd(&cur[c], 1);
    ENT[pos] = PAY[k];
  }
}

// ---- degrees from CSR (no atomics) ----
__global__ void degE_kernel(const i2* __restrict__ ENTA, const int* __restrict__ offE,
                            const float* __restrict__ WMf, float* __restrict__ sc_e, int E) {
  int c = blockIdx.x * 256 + threadIdx.x;
  if (c >= E) return;
  int k0 = offE[c], k1 = offE[c + 1];
  float s = 0.f;
  for (int k = k0; k < k1; ++k) s += __int_as_float(ENTA[k][1]);
  sc_e[c] = WMf[c] / (s + 1e-8f);
}

__global__ void degN_kernel(const i2* __restrict__ ENTB, const int* __restrict__ offN,
                            const float* __restrict__ WMf, float* __restrict__ nd, int N) {
  int r = blockIdx.x * 256 + threadIdx.x;
  if (r >= N) return;
  int k0 = offN[r], k1 = offN[r + 1];
  float s = 0.f;
  for (int k = k0; k < k1; ++k) s += WMf[ENTB[k][0]];
  nd[r] = rsqrtf(s + 1e-8f);
}

// ---- MFMA GEMM v2: LDS-staged weights, 128 rows/block ----
// out_bf16[N,128] = rowScale?*(relu?)(A[N,K] @ Wt^T + bias); Wt[128][K] bf16.
// 4 waves; wave wv owns rows [blk*128+wv*32, +32) as two 16-row MFMA tiles.
// Wt staged in 128-k phases into 32KB LDS, XOR-swizzled (byte ^= (row&7)<<4)
// so the stride-256B ds_read_b128 B-fragment reads are <=2-way bank conflict.
__global__ __launch_bounds__(256) void gemm_mfma2(
    const void* __restrict__ Aptr, const unsigned short* __restrict__ Wt,
    const float* __restrict__ bias, unsigned short* __restrict__ out,
    int Nrows, int K, const int* __restrict__ flags, int relu,
    const float* __restrict__ rowScale) {
  __shared__ unsigned short Bs[128 * 128];   // 32KB, [row][kl] swizzled
  const int tid = threadIdx.x;
  const int wv = tid >> 6, ln = tid & 63;
  const int lr = ln & 15;
  const int lk = (ln >> 4) << 3;
  const int rowBase = blockIdx.x * 128 + wv * 32;
  const int aF32 = flags ? (flags[0] ? 0 : 1) : 0;

  f32x4 acc[2][8];
#pragma unroll
  for (int t = 0; t < 2; ++t)
#pragma unroll
    for (int n = 0; n < 8; ++n) acc[t][n] = (f32x4)0.f;

  int ar[2];
#pragma unroll
  for (int t = 0; t < 2; ++t) {
    int r = rowBase + t * 16 + lr;
    ar[t] = (r < Nrows) ? r : (Nrows - 1);
  }

  auto loadA = [&](int kg, s8b* dst) {
#pragma unroll
    for (int t = 0; t < 2; ++t) {
      if (aF32) {
        const float* ap = (const float*)Aptr + (size_t)ar[t] * K + kg;
        f4 u0 = *reinterpret_cast<const f4*>(ap);
        f4 u1 = *reinterpret_cast<const f4*>(ap + 4);
#pragma unroll
        for (int j = 0; j < 4; ++j) {
          dst[t][j]     = (short)f2bf(u0[j]);
          dst[t][4 + j] = (short)f2bf(u1[j]);
        }
      } else {
        dst[t] = *reinterpret_cast<const s8b*>(
            (const unsigned short*)Aptr + (size_t)ar[t] * K + kg);
      }
    }
  };

  s8b aCur[2], aNxt[2];
  loadA(lk, aCur);

  for (int kp = 0; kp < K; kp += 128) {
    const int plen = (K - kp < 128) ? (K - kp) : 128;
    // stage Wt[:, kp..kp+plen) -> Bs (swizzled), 16B chunks
    const int nch = (128 * plen) >> 3;
    for (int ch = tid; ch < nch; ch += 256) {
      int row = ch >> 4;             // plen==128: 16 chunks/row
      int klc = (ch & 15) << 3;
      if (plen != 128) { row = (ch << 3) / plen; klc = (ch << 3) - row * plen; }
      us8 v = *reinterpret_cast<const us8*>(Wt + (size_t)row * K + kp + klc);
      int byte = ((row << 7) + klc) << 1;
      byte ^= ((row & 7) << 4);
      *reinterpret_cast<us8*>((char*)Bs + byte) = v;
    }
    __syncthreads();

    for (int k0 = 0; k0 < plen; k0 += 32) {
      int kgNext = kp + k0 + 32;
      if (kgNext < K) loadA(kgNext + lk, aNxt);
#pragma unroll
      for (int n = 0; n < 8; ++n) {
        const int brow = n * 16 + lr;
        int byte = ((brow << 7) + k0 + lk) << 1;
        byte ^= ((brow & 7) << 4);
        s8b b = *reinterpret_cast<const s8b*>((const char*)Bs + byte);
        acc[0][n] = __builtin_amdgcn_mfma_f32_16x16x32_bf16(aCur[0], b, acc[0][n], 0, 0, 0);
        acc[1][n] = __builtin_amdgcn_mfma_f32_16x16x32_bf16(aCur[1], b, acc[1][n], 0, 0, 0);
      }
      aCur[0] = aNxt[0]; aCur[1] = aNxt[1];
    }
    __syncthreads();
  }

#pragma unroll
  for (int t = 0; t < 2; ++t) {
    const int orow0 = rowBase + t * 16 + ((ln >> 4) << 2);
#pragma unroll
    for (int n = 0; n < 8; ++n) {
      const int col = n * 16 + lr;
      const float bv = bias[col];
#pragma unroll
      for (int r = 0; r < 4; ++r) {
        int row = orow0 + r;
        if (row >= Nrows) continue;
        float s = acc[t][n][r] + bv;
        if (relu) s = fmaxf(s, 0.f);
        if (rowScale) s *= rowScale[row];
        out[(size_t)row * 128 + col] = f2bf(s);
      }
    }
  }
}

// ---- gather A: HF[c,:] = sc_e[c] * sum_k ew_k * X[src_k,:] ----
__global__ __launch_bounds__(256) void gather_edge2(
    const int* __restrict__ off, const i2* __restrict__ ENT,
    const float* __restrict__ sc_e, const unsigned short* __restrict__ X,
    unsigned short* __restrict__ out, int nseg) {
  int seg = blockIdx.x * 4 + (threadIdx.x >> 6);
  if (seg >= nseg) return;
  int d = (threadIdx.x & 63) << 1;
  int k0 = off[seg], k1 = off[seg + 1];
  float a0 = 0.f, a1 = 0.f;
  int k = k0;
  for (; k + 4 <= k1; k += 4) {
    i2 e0 = ENT[k], e1 = ENT[k + 1], e2 = ENT[k + 2], e3 = ENT[k + 3];
    us2 v0 = *reinterpret_cast<const us2*>(X + (size_t)e0[0] * 128 + d);
    us2 v1 = *reinterpret_cast<const us2*>(X + (size_t)e1[0] * 128 + d);
    us2 v2 = *reinterpret_cast<const us2*>(X + (size_t)e2[0] * 128 + d);
    us2 v3 = *reinterpret_cast<const us2*>(X + (size_t)e3[0] * 128 + d);
    float c0 = __int_as_float(e0[1]), c1 = __int_as_float(e1[1]);
    float c2 = __int_as_float(e2[1]), c3 = __int_as_float(e3[1]);
    a0 += c0 * bf2f(v0[0]); a1 += c0 * bf2f(v0[1]);
    a0 += c1 * bf2f(v1[0]); a1 += c1 * bf2f(v1[1]);
    a0 += c2 * bf2f(v2[0]); a1 += c2 * bf2f(v2[1]);
    a0 += c3 * bf2f(v3[0]); a1 += c3 * bf2f(v3[1]);
  }
  for (; k < k1; ++k) {
    i2 e = ENT[k];
    us2 v = *reinterpret_cast<const us2*>(X + (size_t)e[0] * 128 + d);
    float c = __int_as_float(e[1]);
    a0 += c * bf2f(v[0]); a1 += c * bf2f(v[1]);
  }
  float sc = sc_e[seg];
  us2 o; o[0] = f2bf(sc * a0); o[1] = f2bf(sc * a1);
  *reinterpret_cast<us2*>(out + (size_t)seg * 128 + d) = o;
}

// ---- gather B + h = relu(h + nd[r]*sum) ----
__global__ __launch_bounds__(256) void gather_node2(
    const int* __restrict__ off, const i2* __restrict__ ENT,
    const float* __restrict__ nd, const unsigned short* __restrict__ HF,
    const unsigned short* __restrict__ H, void* __restrict__ out,
    int nseg, int outF32) {
  int seg = blockIdx.x * 4 + (threadIdx.x >> 6);
  if (seg >= nseg) return;
  int d = (threadIdx.x & 63) << 1;
  int k0 = off[seg], k1 = off[seg + 1];
  float a0 = 0.f, a1 = 0.f;
  int k = k0;
  for (; k + 4 <= k1; k += 4) {
    i2 e0 = ENT[k], e1 = ENT[k + 1], e2 = ENT[k + 2], e3 = ENT[k + 3];
    us2 v0 = *reinterpret_cast<const us2*>(HF + (size_t)e0[0] * 128 + d);
    us2 v1 = *reinterpret_cast<const us2*>(HF + (size_t)e1[0] * 128 + d);
    us2 v2 = *reinterpret_cast<const us2*>(HF + (size_t)e2[0] * 128 + d);
    us2 v3 = *reinterpret_cast<const us2*>(HF + (size_t)e3[0] * 128 + d);
    float c0 = __int_as_float(e0[1]), c1 = __int_as_float(e1[1]);
    float c2 = __int_as_float(e2[1]), c3 = __int_as_float(e3[1]);
    a0 += c0 * bf2f(v0[0]); a1 += c0 * bf2f(v0[1]);
    a0 += c1 * bf2f(v1[0]); a1 += c1 * bf2f(v1[1]);
    a0 += c2 * bf2f(v2[0]); a1 += c2 * bf2f(v2[1]);
    a0 += c3 * bf2f(v3[0]); a1 += c3 * bf2f(v3[1]);
  }
  for (; k < k1; ++k) {
    i2 e = ENT[k];
    us2 v = *reinterpret_cast<const us2*>(HF + (size_t)e[0] * 128 + d);
    float c = __int_as_float(e[1]);
    a0 += c * bf2f(v[0]); a1 += c * bf2f(v[1]);
  }
  float s = nd[seg];
  us2 h = *reinterpret_cast<const us2*>(H + (size_t)seg * 128 + d);
  float r0 = fmaxf(bf2f(h[0]) + s * a0, 0.f);
  float r1 = fmaxf(bf2f(h[1]) + s * a1, 0.f);
  if (outF32) {
    f2 o; o[0] = r0; o[1] = r1;
    *reinterpret_cast<f2*>((float*)out + (size_t)seg * 128 + d) = o;
  } else {
    us2 o; o[0] = f2bf(r0); o[1] = f2bf(r1);
    *reinterpret_cast<us2*>((unsigned short*)out + (size_t)seg * 128 + d) = o;
  }
}

extern "C" void kernel_launch(void* const* d_in, const int* in_sizes, int n_in,
                              void* d_out, int out_size, void* d_ws, size_t ws_size,
                              hipStream_t stream) {
  const void* x   = d_in[0];
  const void* hei = d_in[1];
  const void* wM  = d_in[2];
  const void* ew  = d_in[3];
  const void* fcw = d_in[4];
  const void* fcb = d_in[5];
  const void* cw  = d_in[6];
  const void* cb  = d_in[7];

  const int IN_DIM = 256, D = 128;
  const int N = in_sizes[0] / IN_DIM;
  const int M = in_sizes[1] / 2;
  const int E = in_sizes[2];
  const int L = in_sizes[6] / (D * D);

  const int nbE = (E + 127) >> CW_SHIFT;
  const int nbN = (N + 127) >> CW_SHIFT;
  const int nblk = (M + CH - 1) / CH;

  float* w = (float*)d_ws;
  size_t o = 0;
  auto alloc = [&](size_t n) { float* p = w + o; o += (n + 3) & ~(size_t)3; return p; };

  // R region: XT+HF later; BIN arrays earlier (disjoint in time)
  float* R = alloc((size_t)(N + E) * D / 2);
  unsigned short* XT = (unsigned short*)R;
  unsigned short* HF = XT + (size_t)N * D;
  int* KEYA = (int*)R;
  i2*  PAYA = (i2*)(KEYA + M);
  int* KEYB = (int*)(PAYA + M);
  i2*  PAYB = (i2*)(KEYB + M);

  unsigned short* H  = (unsigned short*)alloc((size_t)N * D / 2);
  int*   ROW  = (int*)alloc(M);
  int*   COL  = (int*)alloc(M);
  float* EWf  = alloc(M);
  i2*    ENTA = (i2*)alloc((size_t)M * 2);
  i2*    ENTB = (i2*)alloc((size_t)M * 2);
  int*   cntA = (int*)alloc((size_t)nbE * nblk);
  int*   cntB = (int*)alloc((size_t)nbN * nblk);
  int*   btotA = (int*)alloc(nbE + 2);
  int*   btotB = (int*)alloc(nbN + 2);
  int*   bbaseA = (int*)alloc(nbE + 2);
  int*   bbaseB = (int*)alloc(nbN + 2);
  float* ND   = alloc(N);
  float* SCE  = alloc(E);
  int*   offE = (int*)alloc(E + 1);
  int*   offN = (int*)alloc(N + 1);
  float* WMf  = alloc(E);
  unsigned short* FCWT = (unsigned short*)alloc((size_t)IN_DIM * D / 2);
  float* FCB  = alloc(D);
  unsigned short* CWT = (unsigned short*)alloc((size_t)L * D * D / 2);
  float* CBf  = alloc((size_t)L * D);
  int*   FLAGS = (int*)alloc(16);

  detect_kernel<<<1, 64, 0, stream>>>((const unsigned int*)x, (const unsigned int*)hei, FLAGS);

  cvt_bin_count<<<nblk, 256, 0, stream>>>(hei, ew, M, ROW, COL, EWf,
                                          cntA, cntB, nbE, nbN, nblk, FLAGS);
  cvt_f32<<<(E + 255) / 256, 256, 0, stream>>>(wM, WMf, E, FLAGS);
  cvt_wt<<<(IN_DIM * D + 255) / 256, 256, 0, stream>>>(fcw, FCWT, IN_DIM, D, 0, FLAGS);
  cvt_f32<<<1, 256, 0, stream>>>(fcb, FCB, D, FLAGS);
  for (int l = 0; l < L; ++l)
    cvt_wt<<<(D * D + 255) / 256, 256, 0, stream>>>(cw, CWT + (size_t)l * D * D,
                                                    D, D, l * D * D, FLAGS);
  cvt_f32<<<(L * D + 255) / 256, 256, 0, stream>>>(cb, CBf, L * D, FLAGS);

  scanA<<<nbE, 512, 0, stream>>>(cntA, btotA, nblk);
  scanA<<<nbN, 512, 0, stream>>>(cntB, btotB, nblk);
  scanB<<<1, 512, 0, stream>>>(btotA, bbaseA, nbE);
  scanB<<<1, 512, 0, stream>>>(btotB, bbaseB, nbN);

  binscatter<<<nblk, 256, 0, stream>>>(ROW, COL, EWf, M, cntA, bbaseA, cntB, bbaseB,
                                       KEYA, PAYA, KEYB, PAYB, nbE, nbN, nblk);

  finalize<<<nbE, 256, 0, stream>>>(KEYA, PAYA, bbaseA, ENTA, offE, E);
  finalize<<<nbN, 256, 0, stream>>>(KEYB, PAYB, bbaseB, ENTB, offN, N);

  degE_kernel<<<(E + 255) / 256, 256, 0, stream>>>(ENTA, offE, WMf, SCE, E);
  degN_kernel<<<(N + 255) / 256, 256, 0, stream>>>(ENTB, offN, WMf, ND, N);

  // h0 = relu(x @ fc_w + fc_b)
  gemm_mfma2<<<(N + 127) / 128, 256, 0, stream>>>(x, FCWT, FCB, H, N, IN_DIM,
                                                  FLAGS, 1, nullptr);

  int segBlkE = (E + 3) / 4, segBlkN = (N + 3) / 4;
  for (int l = 0; l < L; ++l) {
    gemm_mfma2<<<(N + 127) / 128, 256, 0, stream>>>(H, CWT + (size_t)l * D * D,
                                                    CBf + (size_t)l * D, XT, N, D,
                                                    (const int*)nullptr, 0, ND);
    gather_edge2<<<segBlkE, 256, 0, stream>>>(offE, ENTA, SCE, XT, HF, E);
    gather_node2<<<segBlkN, 256, 0, stream>>>(
        offN, ENTB, ND, HF, H,
        (l == L - 1) ? d_out : (void*)H, N, (l == L - 1) ? 1 : 0);
  }
}

// Round 9
// 385.061 us; speedup vs baseline: 2.4542x; 1.0880x over previous
//
#include <hip/hip_runtime.h>
#include <hip/hip_bf16.h>
#include <stdint.h>

typedef __attribute__((ext_vector_type(4))) float f4;
typedef __attribute__((ext_vector_type(2))) float f2;
typedef __attribute__((ext_vector_type(2))) int i2;
typedef __attribute__((ext_vector_type(8))) unsigned short us8;
typedef __attribute__((ext_vector_type(4))) unsigned short us4;
typedef __attribute__((ext_vector_type(2))) unsigned short us2;
typedef __attribute__((ext_vector_type(8))) short s8b;    // MFMA A/B frag (8 bf16)
typedef __attribute__((ext_vector_type(4))) float f32x4;  // MFMA C/D frag

#define CW_SHIFT 7            // 128 cols per bucket
#define CH 2048               // edges per block in bin phases

__device__ __forceinline__ float bf2f(unsigned short u) {
  union { unsigned int i; float f; } t; t.i = ((unsigned int)u) << 16; return t.f;
}
__device__ __forceinline__ unsigned short f2bf(float f) {
  union { float f; unsigned int i; } t; t.f = f;
  unsigned int u = t.i;
  return (unsigned short)((u + 0x7FFFu + ((u >> 16) & 1u)) >> 16);
}
__device__ __forceinline__ float cvtload(const void* p, int i, int f16) {
  return f16 ? bf2f(((const unsigned short*)p)[i]) : ((const float*)p)[i];
}

// ---- dtype detection ----
__global__ void detect_kernel(const unsigned int* __restrict__ xb,
                              const unsigned int* __restrict__ ib,
                              int* __restrict__ flags) {
  if (threadIdx.x == 0) {
    int cnt = 0;
    for (int i = 0; i < 256; ++i) {
      unsigned int e = (xb[i] >> 7) & 0xffu;
      if (e >= 110u && e <= 135u) ++cnt;
    }
    flags[0] = (cnt >= 180) ? 1 : 0;
    int zc = 0;
    for (int i = 0; i < 128; ++i) if (ib[2 * i + 1] == 0u) ++zc;
    flags[1] = (zc >= 120) ? 1 : 0;
  }
}

// ---- fused parameter convert: wM, fc_w^T, fc_b, conv_w^T, conv_b ----
__global__ void cvt_params(const void* __restrict__ wM, const void* __restrict__ fcw,
                           const void* __restrict__ fcb, const void* __restrict__ cw,
                           const void* __restrict__ cb,
                           float* __restrict__ WMf, unsigned short* __restrict__ FCWT,
                           float* __restrict__ FCB, unsigned short* __restrict__ CWT,
                           float* __restrict__ CBf,
                           int E, int L, const int* __restrict__ flags) {
  const int IN_DIM = 256, D = 128;
  int i = blockIdx.x * 256 + threadIdx.x;
  const int f16 = flags[0];
  if (i < E) { WMf[i] = cvtload(wM, i, f16); return; }
  i -= E;
  if (i < IN_DIM * D) {  // FCWT[c*256 + k] = fcw[k*128 + c]
    int c = i >> 8, k = i & 255;
    FCWT[i] = f2bf(cvtload(fcw, k * D + c, f16));
    return;
  }
  i -= IN_DIM * D;
  if (i < D) { FCB[i] = cvtload(fcb, i, f16); return; }
  i -= D;
  if (i < L * D * D) {  // CWT[l*16384 + c*128 + k] = cw[l*16384 + k*128 + c]
    int l = i >> 14, rem = i & 16383;
    int c = rem >> 7, k = rem & 127;
    CWT[i] = f2bf(cvtload(cw, l * D * D + k * D + c, f16));
    return;
  }
  i -= L * D * D;
  if (i < L * D) CBf[i] = cvtload(cb, i, f16);
}

// ---- phase 1: convert indices/edge-weights + per-(block,bucket) histograms ----
__global__ __launch_bounds__(256) void cvt_bin_count(
    const void* __restrict__ hei, const void* __restrict__ ew, int M,
    int* __restrict__ ROW, int* __restrict__ COL, float* __restrict__ EWf,
    int* __restrict__ cntA, int* __restrict__ cntB,
    int nbE, int nbN, int nblk, const int* __restrict__ flags) {
  __shared__ int hA[512];
  __shared__ int hB[512];
  const int tid = threadIdx.x, blk = blockIdx.x;
  for (int b = tid; b < 512; b += 256) { hA[b] = 0; hB[b] = 0; }
  __syncthreads();
  const int i64 = flags[1], f16 = flags[0];
#pragma unroll
  for (int i = 0; i < CH / 256; ++i) {
    int m = blk * CH + i * 256 + tid;
    if (m >= M) break;
    int r, c;
    if (i64) {
      r = (int)((const long long*)hei)[m];
      c = (int)((const long long*)hei)[M + m];
    } else {
      r = ((const int*)hei)[m];
      c = ((const int*)hei)[M + m];
    }
    ROW[m] = r; COL[m] = c;
    EWf[m] = f16 ? bf2f(((const unsigned short*)ew)[m]) : ((const float*)ew)[m];
    atomicAdd(&hA[c >> CW_SHIFT], 1);
    atomicAdd(&hB[r >> CW_SHIFT], 1);
  }
  __syncthreads();
  for (int b = tid; b < nbE; b += 256) cntA[b * nblk + blk] = hA[b];
  for (int b = tid; b < nbN; b += 256) cntB[b * nblk + blk] = hB[b];
}

// ---- scanA: per-bucket exclusive scan (in place) over nblk block counts ----
__global__ __launch_bounds__(512) void scanA(int* __restrict__ cnt,
                                             int* __restrict__ btot, int nblk) {
  __shared__ int sc[512];
  const int tid = threadIdx.x, b = blockIdx.x;
  int v = (tid < nblk) ? cnt[b * nblk + tid] : 0;
  sc[tid] = v;
  __syncthreads();
  for (int s = 1; s < 512; s <<= 1) {
    int t = (tid >= s) ? sc[tid - s] : 0;
    __syncthreads();
    sc[tid] += t;
    __syncthreads();
  }
  if (tid < nblk) cnt[b * nblk + tid] = sc[tid] - v;
  if (tid == 511) btot[b] = sc[511];
}

// ---- scanB: single-block exclusive scan of bucket totals -> bbase[nb+1] ----
__global__ __launch_bounds__(512) void scanB(const int* __restrict__ btot,
                                             int* __restrict__ bbase, int nb) {
  __shared__ int sc[512];
  const int tid = threadIdx.x;
  int v = (tid < nb) ? btot[tid] : 0;
  sc[tid] = v;
  __syncthreads();
  for (int s = 1; s < 512; s <<= 1) {
    int t = (tid >= s) ? sc[tid - s] : 0;
    __syncthreads();
    sc[tid] += t;
    __syncthreads();
  }
  if (tid < nb) bbase[tid] = sc[tid] - v;
  if (tid == 511) bbase[nb] = sc[511];
}

// ---- phase 2: scatter edges into bucket-major binned arrays ----
__global__ __launch_bounds__(256) void binscatter(
    const int* __restrict__ ROW, const int* __restrict__ COL,
    const float* __restrict__ EWf, int M,
    const int* __restrict__ cntA, const int* __restrict__ bbaseA,
    const int* __restrict__ cntB, const int* __restrict__ bbaseB,
    int* __restrict__ KEYA, i2* __restrict__ PAYA,
    int* __restrict__ KEYB, i2* __restrict__ PAYB,
    int nbE, int nbN, int nblk) {
  __shared__ int baseA[512];
  __shared__ int baseB[512];
  const int tid = threadIdx.x, blk = blockIdx.x;
  for (int b = tid; b < nbE; b += 256) baseA[b] = bbaseA[b] + cntA[b * nblk + blk];
  for (int b = tid; b < nbN; b += 256) baseB[b] = bbaseB[b] + cntB[b * nblk + blk];
  __syncthreads();
#pragma unroll
  for (int i = 0; i < CH / 256; ++i) {
    int m = blk * CH + i * 256 + tid;
    if (m >= M) break;
    int r = ROW[m], c = COL[m];
    int e = __float_as_int(EWf[m]);
    int pA = atomicAdd(&baseA[c >> CW_SHIFT], 1);
    KEYA[pA] = c;
    i2 ea; ea[0] = r; ea[1] = e; PAYA[pA] = ea;
    int pB = atomicAdd(&baseB[r >> CW_SHIFT], 1);
    KEYB[pB] = r;
    i2 eb; eb[0] = c; eb[1] = e; PAYB[pB] = eb;
  }
}

// ---- phase 3: per-bucket finalize -> CSR entries + offsets + degree scales ----
// modeB=0: outScale[c] = WMf[c]/(sum(ew)+1e-8)  (edge side)
// modeB=1: outScale[r] = rsqrt(sum(WMf[src])+1e-8)  (node side)
__global__ __launch_bounds__(256) void finalize2(
    const int* __restrict__ KEY, const i2* __restrict__ PAY,
    const int* __restrict__ bbase, i2* __restrict__ ENT,
    int* __restrict__ off, int nseg,
    const float* __restrict__ WMf, float* __restrict__ outScale, int modeB) {
  __shared__ int cnt[128];
  __shared__ int sc[128];
  __shared__ int cur[128];
  __shared__ float fsum[128];
  const int tid = threadIdx.x, b = blockIdx.x;
  const int bs = bbase[b], be = bbase[b + 1];
  const int cb = b << CW_SHIFT;
  const int cw = min(128, nseg - cb);
  if (tid < 128) { cnt[tid] = 0; fsum[tid] = 0.f; }
  __syncthreads();
  for (int k = bs + tid; k < be; k += 256) atomicAdd(&cnt[KEY[k] - cb], 1);
  __syncthreads();
  if (tid < 128) sc[tid] = cnt[tid];
  __syncthreads();
  for (int s = 1; s < 128; s <<= 1) {
    int t = (tid < 128 && tid >= s) ? sc[tid - s] : 0;
    __syncthreads();
    if (tid < 128) sc[tid] += t;
    __syncthreads();
  }
  if (tid < 128) {
    int start = bs + sc[tid] - cnt[tid];
    cur[tid] = start;
    if (tid < cw) off[cb + tid] = start;
  }
  if (b == gridDim.x - 1 && tid == 0) off[nseg] = be;
  __syncthreads();
  for (int k = bs + tid; k < be; k += 256) {
    int c = KEY[k] - cb;
    i2 p = PAY[k];
    int pos = atomicAdd(&cur[c], 1);
    ENT[pos] = p;
    float add = modeB ? WMf[p[0]] : __int_as_float(p[1]);
    atomicAdd(&fsum[c], add);
  }
  __syncthreads();
  if (tid < cw) {
    float s = fsum[tid] + 1e-8f;
    outScale[cb + tid] = modeB ? rsqrtf(s) : (WMf[cb + tid] / s);
  }
}

// ---- MFMA GEMM v3: LDS-staged weights + fully hoisted A loads ----
// out_bf16[N,128] = rowScale?*(relu?)(A[N,K] @ Wt^T + bias); Wt[128][K] bf16.
// 4 waves x 2 row-tiles; all KS A-fragments issued before the k-loop (16B x 2*KS
// per lane in flight -> MLP-saturating). B via swizzled LDS ds_read_b128.
template<int KS>
__global__ __launch_bounds__(256) void gemm_mfma3(
    const void* __restrict__ Aptr, const unsigned short* __restrict__ Wt,
    const float* __restrict__ bias, unsigned short* __restrict__ out,
    int Nrows, const int* __restrict__ flags, int relu,
    const float* __restrict__ rowScale) {
  constexpr int K = KS * 32;
  constexpr int KC = K / 8;            // 16B chunks per Wt row
  extern __shared__ unsigned short Bs[];
  const int tid = threadIdx.x;
  const int wv = tid >> 6, ln = tid & 63;
  const int lr = ln & 15;
  const int lk = (ln >> 4) << 3;
  const int rowBase = blockIdx.x * 128 + wv * 32;
  const int aF32 = flags ? (flags[0] ? 0 : 1) : 0;

  int ar[2];
#pragma unroll
  for (int t = 0; t < 2; ++t) {
    int r = rowBase + t * 16 + lr;
    ar[t] = (r < Nrows) ? r : (Nrows - 1);
  }

  s8b aR[2][KS];
  if (!aF32) {
#pragma unroll
    for (int t = 0; t < 2; ++t)
#pragma unroll
      for (int ks = 0; ks < KS; ++ks)
        aR[t][ks] = *reinterpret_cast<const s8b*>(
            (const unsigned short*)Aptr + (size_t)ar[t] * K + ks * 32 + lk);
  } else {
#pragma unroll
    for (int t = 0; t < 2; ++t)
#pragma unroll
      for (int ks = 0; ks < KS; ++ks) {
        const float* ap = (const float*)Aptr + (size_t)ar[t] * K + ks * 32 + lk;
        f4 u0 = *reinterpret_cast<const f4*>(ap);
        f4 u1 = *reinterpret_cast<const f4*>(ap + 4);
#pragma unroll
        for (int j = 0; j < 4; ++j) {
          aR[t][ks][j]     = (short)f2bf(u0[j]);
          aR[t][ks][4 + j] = (short)f2bf(u1[j]);
        }
      }
  }

  // stage Wt (swizzled): consecutive tid -> consecutive 16B chunks
#pragma unroll
  for (int it = 0; it < (128 * KC + 255) / 256; ++it) {
    int ch = it * 256 + tid;
    if (ch < 128 * KC) {
      int row = ch / KC, kc = (ch % KC) << 3;
      us8 v = *reinterpret_cast<const us8*>(Wt + (size_t)row * K + kc);
      int byte = ((row * K + kc) << 1) ^ ((row & 7) << 4);
      *reinterpret_cast<us8*>((char*)Bs + byte) = v;
    }
  }
  __syncthreads();

  f32x4 acc[2][8];
#pragma unroll
  for (int t = 0; t < 2; ++t)
#pragma unroll
    for (int n = 0; n < 8; ++n) acc[t][n] = (f32x4)0.f;

#pragma unroll
  for (int ks = 0; ks < KS; ++ks) {
#pragma unroll
    for (int n = 0; n < 8; ++n) {
      const int brow = n * 16 + lr;
      int byte = ((brow * K + ks * 32 + lk) << 1) ^ ((brow & 7) << 4);
      s8b b = *reinterpret_cast<const s8b*>((const char*)Bs + byte);
      acc[0][n] = __builtin_amdgcn_mfma_f32_16x16x32_bf16(aR[0][ks], b, acc[0][n], 0, 0, 0);
      acc[1][n] = __builtin_amdgcn_mfma_f32_16x16x32_bf16(aR[1][ks], b, acc[1][n], 0, 0, 0);
    }
  }

#pragma unroll
  for (int t = 0; t < 2; ++t) {
    const int orow0 = rowBase + t * 16 + ((ln >> 4) << 2);
#pragma unroll
    for (int n = 0; n < 8; ++n) {
      const int col = n * 16 + lr;
      const float bv = bias[col];
#pragma unroll
      for (int r = 0; r < 4; ++r) {
        int row = orow0 + r;
        if (row >= Nrows) continue;
        float s = acc[t][n][r] + bv;
        if (relu) s = fmaxf(s, 0.f);
        if (rowScale) s *= rowScale[row];
        out[(size_t)row * 128 + col] = f2bf(s);
      }
    }
  }
}

// ---- gather A: HF[c,:] = sc_e[c] * sum_k ew_k * X[src_k,:] ----
__global__ __launch_bounds__(256) void gather_edge2(
    const int* __restrict__ off, const i2* __restrict__ ENT,
    const float* __restrict__ sc_e, const unsigned short* __restrict__ X,
    unsigned short* __restrict__ out, int nseg) {
  int seg = blockIdx.x * 4 + (threadIdx.x >> 6);
  if (seg >= nseg) return;
  int d = (threadIdx.x & 63) << 1;
  int k0 = off[seg], k1 = off[seg + 1];
  float a0 = 0.f, a1 = 0.f;
  int k = k0;
  for (; k + 4 <= k1; k += 4) {
    i2 e0 = ENT[k], e1 = ENT[k + 1], e2 = ENT[k + 2], e3 = ENT[k + 3];
    us2 v0 = *reinterpret_cast<const us2*>(X + (size_t)e0[0] * 128 + d);
    us2 v1 = *reinterpret_cast<const us2*>(X + (size_t)e1[0] * 128 + d);
    us2 v2 = *reinterpret_cast<const us2*>(X + (size_t)e2[0] * 128 + d);
    us2 v3 = *reinterpret_cast<const us2*>(X + (size_t)e3[0] * 128 + d);
    float c0 = __int_as_float(e0[1]), c1 = __int_as_float(e1[1]);
    float c2 = __int_as_float(e2[1]), c3 = __int_as_float(e3[1]);
    a0 += c0 * bf2f(v0[0]); a1 += c0 * bf2f(v0[1]);
    a0 += c1 * bf2f(v1[0]); a1 += c1 * bf2f(v1[1]);
    a0 += c2 * bf2f(v2[0]); a1 += c2 * bf2f(v2[1]);
    a0 += c3 * bf2f(v3[0]); a1 += c3 * bf2f(v3[1]);
  }
  for (; k < k1; ++k) {
    i2 e = ENT[k];
    us2 v = *reinterpret_cast<const us2*>(X + (size_t)e[0] * 128 + d);
    float c = __int_as_float(e[1]);
    a0 += c * bf2f(v[0]); a1 += c * bf2f(v[1]);
  }
  float sc = sc_e[seg];
  us2 o; o[0] = f2bf(sc * a0); o[1] = f2bf(sc * a1);
  *reinterpret_cast<us2*>(out + (size_t)seg * 128 + d) = o;
}

// ---- gather B + h = relu(h + nd[r]*sum) ----
__global__ __launch_bounds__(256) void gather_node2(
    const int* __restrict__ off, const i2* __restrict__ ENT,
    const float* __restrict__ nd, const unsigned short* __restrict__ HF,
    const unsigned short* __restrict__ H, void* __restrict__ out,
    int nseg, int outF32) {
  int seg = blockIdx.x * 4 + (threadIdx.x >> 6);
  if (seg >= nseg) return;
  int d = (threadIdx.x & 63) << 1;
  int k0 = off[seg], k1 = off[seg + 1];
  float a0 = 0.f, a1 = 0.f;
  int k = k0;
  for (; k + 4 <= k1; k += 4) {
    i2 e0 = ENT[k], e1 = ENT[k + 1], e2 = ENT[k + 2], e3 = ENT[k + 3];
    us2 v0 = *reinterpret_cast<const us2*>(HF + (size_t)e0[0] * 128 + d);
    us2 v1 = *reinterpret_cast<const us2*>(HF + (size_t)e1[0] * 128 + d);
    us2 v2 = *reinterpret_cast<const us2*>(HF + (size_t)e2[0] * 128 + d);
    us2 v3 = *reinterpret_cast<const us2*>(HF + (size_t)e3[0] * 128 + d);
    float c0 = __int_as_float(e0[1]), c1 = __int_as_float(e1[1]);
    float c2 = __int_as_float(e2[1]), c3 = __int_as_float(e3[1]);
    a0 += c0 * bf2f(v0[0]); a1 += c0 * bf2f(v0[1]);
    a0 += c1 * bf2f(v1[0]); a1 += c1 * bf2f(v1[1]);
    a0 += c2 * bf2f(v2[0]); a1 += c2 * bf2f(v2[1]);
    a0 += c3 * bf2f(v3[0]); a1 += c3 * bf2f(v3[1]);
  }
  for (; k < k1; ++k) {
    i2 e = ENT[k];
    us2 v = *reinterpret_cast<const us2*>(HF + (size_t)e[0] * 128 + d);
    float c = __int_as_float(e[1]);
    a0 += c * bf2f(v[0]); a1 += c * bf2f(v[1]);
  }
  float s = nd[seg];
  us2 h = *reinterpret_cast<const us2*>(H + (size_t)seg * 128 + d);
  float r0 = fmaxf(bf2f(h[0]) + s * a0, 0.f);
  float r1 = fmaxf(bf2f(h[1]) + s * a1, 0.f);
  if (outF32) {
    f2 o; o[0] = r0; o[1] = r1;
    *reinterpret_cast<f2*>((float*)out + (size_t)seg * 128 + d) = o;
  } else {
    us2 o; o[0] = f2bf(r0); o[1] = f2bf(r1);
    *reinterpret_cast<us2*>((unsigned short*)out + (size_t)seg * 128 + d) = o;
  }
}

extern "C" void kernel_launch(void* const* d_in, const int* in_sizes, int n_in,
                              void* d_out, int out_size, void* d_ws, size_t ws_size,
                              hipStream_t stream) {
  const void* x   = d_in[0];
  const void* hei = d_in[1];
  const void* wM  = d_in[2];
  const void* ew  = d_in[3];
  const void* fcw = d_in[4];
  const void* fcb = d_in[5];
  const void* cw  = d_in[6];
  const void* cb  = d_in[7];

  const int IN_DIM = 256, D = 128;
  const int N = in_sizes[0] / IN_DIM;
  const int M = in_sizes[1] / 2;
  const int E = in_sizes[2];
  const int L = in_sizes[6] / (D * D);

  const int nbE = (E + 127) >> CW_SHIFT;
  const int nbN = (N + 127) >> CW_SHIFT;
  const int nblk = (M + CH - 1) / CH;

  float* w = (float*)d_ws;
  size_t o = 0;
  auto alloc = [&](size_t n) { float* p = w + o; o += (n + 3) & ~(size_t)3; return p; };

  // R region: XT+HF later; BIN arrays earlier (disjoint in time)
  float* R = alloc((size_t)(N + E) * D / 2);
  unsigned short* XT = (unsigned short*)R;
  unsigned short* HF = XT + (size_t)N * D;
  int* KEYA = (int*)R;
  i2*  PAYA = (i2*)(KEYA + M);
  int* KEYB = (int*)(PAYA + M);
  i2*  PAYB = (i2*)(KEYB + M);

  unsigned short* H  = (unsigned short*)alloc((size_t)N * D / 2);
  int*   ROW  = (int*)alloc(M);
  int*   COL  = (int*)alloc(M);
  float* EWf  = alloc(M);
  i2*    ENTA = (i2*)alloc((size_t)M * 2);
  i2*    ENTB = (i2*)alloc((size_t)M * 2);
  int*   cntA = (int*)alloc((size_t)nbE * nblk);
  int*   cntB = (int*)alloc((size_t)nbN * nblk);
  int*   btotA = (int*)alloc(nbE + 2);
  int*   btotB = (int*)alloc(nbN + 2);
  int*   bbaseA = (int*)alloc(nbE + 2);
  int*   bbaseB = (int*)alloc(nbN + 2);
  float* ND   = alloc(N);
  float* SCE  = alloc(E);
  int*   offE = (int*)alloc(E + 1);
  int*   offN = (int*)alloc(N + 1);
  float* WMf  = alloc(E);
  unsigned short* FCWT = (unsigned short*)alloc((size_t)IN_DIM * D / 2);
  float* FCB  = alloc(D);
  unsigned short* CWT = (unsigned short*)alloc((size_t)L * D * D / 2);
  float* CBf  = alloc((size_t)L * D);
  int*   FLAGS = (int*)alloc(16);

  detect_kernel<<<1, 64, 0, stream>>>((const unsigned int*)x, (const unsigned int*)hei, FLAGS);

  cvt_bin_count<<<nblk, 256, 0, stream>>>(hei, ew, M, ROW, COL, EWf,
                                          cntA, cntB, nbE, nbN, nblk, FLAGS);
  {
    int ntot = E + IN_DIM * D + D + L * D * D + L * D;
    cvt_params<<<(ntot + 255) / 256, 256, 0, stream>>>(wM, fcw, fcb, cw, cb,
                                                       WMf, FCWT, FCB, CWT, CBf,
                                                       E, L, FLAGS);
  }

  scanA<<<nbE, 512, 0, stream>>>(cntA, btotA, nblk);
  scanA<<<nbN, 512, 0, stream>>>(cntB, btotB, nblk);
  scanB<<<1, 512, 0, stream>>>(btotA, bbaseA, nbE);
  scanB<<<1, 512, 0, stream>>>(btotB, bbaseB, nbN);

  binscatter<<<nblk, 256, 0, stream>>>(ROW, COL, EWf, M, cntA, bbaseA, cntB, bbaseB,
                                       KEYA, PAYA, KEYB, PAYB, nbE, nbN, nblk);

  finalize2<<<nbE, 256, 0, stream>>>(KEYA, PAYA, bbaseA, ENTA, offE, E, WMf, SCE, 0);
  finalize2<<<nbN, 256, 0, stream>>>(KEYB, PAYB, bbaseB, ENTB, offN, N, WMf, ND, 1);

  // h0 = relu(x @ fc_w + fc_b)
  gemm_mfma3<8><<<(N + 127) / 128, 256, 128 * 256 * 2, stream>>>(
      x, FCWT, FCB, H, N, FLAGS, 1, nullptr);

  int segBlkE = (E + 3) / 4, segBlkN = (N + 3) / 4;
  for (int l = 0; l < L; ++l) {
    // xt' = nd[r] * (h @ conv_w[l] + conv_b[l])
    gemm_mfma3<4><<<(N + 127) / 128, 256, 128 * 128 * 2, stream>>>(
        H, CWT + (size_t)l * D * D, CBf + (size_t)l * D, XT, N,
        (const int*)nullptr, 0, ND);
    gather_edge2<<<segBlkE, 256, 0, stream>>>(offE, ENTA, SCE, XT, HF, E);
    gather_node2<<<segBlkN, 256, 0, stream>>>(
        offN, ENTB, ND, HF, H,
        (l == L - 1) ? d_out : (void*)H, N, (l == L - 1) ? 1 : 0);
  }
}

// Round 10
// 336.139 us; speedup vs baseline: 2.8114x; 1.1455x over previous
//
#include <hip/hip_runtime.h>
#include <hip/hip_bf16.h>
#include <stdint.h>

typedef __attribute__((ext_vector_type(4))) float f4;
typedef __attribute__((ext_vector_type(2))) float f2;
typedef __attribute__((ext_vector_type(2))) int i2;
typedef __attribute__((ext_vector_type(8))) unsigned short us8;
typedef __attribute__((ext_vector_type(4))) unsigned short us4;
typedef __attribute__((ext_vector_type(2))) unsigned short us2;
typedef __attribute__((ext_vector_type(8))) short s8b;    // MFMA A/B frag (8 bf16)
typedef __attribute__((ext_vector_type(4))) float f32x4;  // MFMA C/D frag

#define CW_SHIFT 7            // 128 cols per bucket
#define CH 2048               // edges per block in bin phases

__device__ __forceinline__ float bf2f(unsigned short u) {
  union { unsigned int i; float f; } t; t.i = ((unsigned int)u) << 16; return t.f;
}
__device__ __forceinline__ unsigned short f2bf(float f) {
  union { float f; unsigned int i; } t; t.f = f;
  unsigned int u = t.i;
  return (unsigned short)((u + 0x7FFFu + ((u >> 16) & 1u)) >> 16);
}
__device__ __forceinline__ float cvtload(const void* p, int i, int f16) {
  return f16 ? bf2f(((const unsigned short*)p)[i]) : ((const float*)p)[i];
}

// ---- dtype detection ----
__global__ void detect_kernel(const unsigned int* __restrict__ xb,
                              const unsigned int* __restrict__ ib,
                              int* __restrict__ flags) {
  if (threadIdx.x == 0) {
    int cnt = 0;
    for (int i = 0; i < 256; ++i) {
      unsigned int e = (xb[i] >> 7) & 0xffu;
      if (e >= 110u && e <= 135u) ++cnt;
    }
    flags[0] = (cnt >= 180) ? 1 : 0;
    int zc = 0;
    for (int i = 0; i < 128; ++i) if (ib[2 * i + 1] == 0u) ++zc;
    flags[1] = (zc >= 120) ? 1 : 0;
  }
}

// ---- fused parameter convert: wM, fc_w^T, fc_b, conv_w^T, conv_b ----
__global__ void cvt_params(const void* __restrict__ wM, const void* __restrict__ fcw,
                           const void* __restrict__ fcb, const void* __restrict__ cw,
                           const void* __restrict__ cb,
                           float* __restrict__ WMf, unsigned short* __restrict__ FCWT,
                           float* __restrict__ FCB, unsigned short* __restrict__ CWT,
                           float* __restrict__ CBf,
                           int E, int L, const int* __restrict__ flags) {
  const int IN_DIM = 256, D = 128;
  int i = blockIdx.x * 256 + threadIdx.x;
  const int f16 = flags[0];
  if (i < E) { WMf[i] = cvtload(wM, i, f16); return; }
  i -= E;
  if (i < IN_DIM * D) {
    int c = i >> 8, k = i & 255;
    FCWT[i] = f2bf(cvtload(fcw, k * D + c, f16));
    return;
  }
  i -= IN_DIM * D;
  if (i < D) { FCB[i] = cvtload(fcb, i, f16); return; }
  i -= D;
  if (i < L * D * D) {
    int l = i >> 14, rem = i & 16383;
    int c = rem >> 7, k = rem & 127;
    CWT[i] = f2bf(cvtload(cw, l * D * D + k * D + c, f16));
    return;
  }
  i -= L * D * D;
  if (i < L * D) CBf[i] = cvtload(cb, i, f16);
}

// ---- phase 1: per-(block,bucket) histograms only (no staging writes) ----
// cntAB layout: [bucket 0..nbE+nbN)[block]; col-buckets first, then row-buckets.
__global__ __launch_bounds__(256) void bin_count(
    const void* __restrict__ hei, int M, int* __restrict__ cntAB,
    int nbE, int nbN, int nblk, const int* __restrict__ flags) {
  __shared__ int hA[512];
  __shared__ int hB[512];
  const int tid = threadIdx.x, blk = blockIdx.x;
  for (int b = tid; b < 512; b += 256) { hA[b] = 0; hB[b] = 0; }
  __syncthreads();
  const int i64 = flags[1];
#pragma unroll
  for (int i = 0; i < CH / 256; ++i) {
    int m = blk * CH + i * 256 + tid;
    if (m >= M) break;
    int r, c;
    if (i64) {
      r = (int)((const long long*)hei)[m];
      c = (int)((const long long*)hei)[M + m];
    } else {
      r = ((const int*)hei)[m];
      c = ((const int*)hei)[M + m];
    }
    atomicAdd(&hA[c >> CW_SHIFT], 1);
    atomicAdd(&hB[r >> CW_SHIFT], 1);
  }
  __syncthreads();
  for (int b = tid; b < nbE; b += 256) cntAB[b * nblk + blk] = hA[b];
  for (int b = tid; b < nbN; b += 256) cntAB[(nbE + b) * nblk + blk] = hB[b];
}

// ---- scanA: per-bucket exclusive scan over nblk block counts (both families) ----
__global__ __launch_bounds__(512) void scanA(int* __restrict__ cnt,
                                             int* __restrict__ btot, int nblk) {
  __shared__ int sc[512];
  const int tid = threadIdx.x, b = blockIdx.x;
  int v = (tid < nblk) ? cnt[b * nblk + tid] : 0;
  sc[tid] = v;
  __syncthreads();
  for (int s = 1; s < 512; s <<= 1) {
    int t = (tid >= s) ? sc[tid - s] : 0;
    __syncthreads();
    sc[tid] += t;
    __syncthreads();
  }
  if (tid < nblk) cnt[b * nblk + tid] = sc[tid] - v;
  if (tid == 511) btot[b] = sc[511];
}

// ---- scanB: 2 blocks; block0 scans A-family totals, block1 B-family ----
__global__ __launch_bounds__(512) void scanB(const int* __restrict__ btot,
                                             int* __restrict__ bbaseA,
                                             int* __restrict__ bbaseB,
                                             int nbE, int nbN) {
  __shared__ int sc[512];
  const int tid = threadIdx.x;
  const int nb = blockIdx.x ? nbN : nbE;
  const int* src = blockIdx.x ? (btot + nbE) : btot;
  int* dst = blockIdx.x ? bbaseB : bbaseA;
  int v = (tid < nb) ? src[tid] : 0;
  sc[tid] = v;
  __syncthreads();
  for (int s = 1; s < 512; s <<= 1) {
    int t = (tid >= s) ? sc[tid - s] : 0;
    __syncthreads();
    sc[tid] += t;
    __syncthreads();
  }
  if (tid < nb) dst[tid] = sc[tid] - v;
  if (tid == 511) dst[nb] = sc[511];
}

// ---- phase 2: decode hei/ew inline + scatter into bucket-major binned arrays ----
__global__ __launch_bounds__(256) void binscatter(
    const void* __restrict__ hei, const void* __restrict__ ew, int M,
    const int* __restrict__ cntAB,
    const int* __restrict__ bbaseA, const int* __restrict__ bbaseB,
    int* __restrict__ KEYA, i2* __restrict__ PAYA,
    int* __restrict__ KEYB, i2* __restrict__ PAYB,
    int nbE, int nbN, int nblk, const int* __restrict__ flags) {
  __shared__ int baseA[512];
  __shared__ int baseB[512];
  const int tid = threadIdx.x, blk = blockIdx.x;
  for (int b = tid; b < nbE; b += 256) baseA[b] = bbaseA[b] + cntAB[b * nblk + blk];
  for (int b = tid; b < nbN; b += 256) baseB[b] = bbaseB[b] + cntAB[(nbE + b) * nblk + blk];
  __syncthreads();
  const int i64 = flags[1], f16 = flags[0];
#pragma unroll
  for (int i = 0; i < CH / 256; ++i) {
    int m = blk * CH + i * 256 + tid;
    if (m >= M) break;
    int r, c;
    if (i64) {
      r = (int)((const long long*)hei)[m];
      c = (int)((const long long*)hei)[M + m];
    } else {
      r = ((const int*)hei)[m];
      c = ((const int*)hei)[M + m];
    }
    int e = __float_as_int(f16 ? bf2f(((const unsigned short*)ew)[m])
                               : ((const float*)ew)[m]);
    int pA = atomicAdd(&baseA[c >> CW_SHIFT], 1);
    KEYA[pA] = c;
    i2 ea; ea[0] = r; ea[1] = e; PAYA[pA] = ea;
    int pB = atomicAdd(&baseB[r >> CW_SHIFT], 1);
    KEYB[pB] = r;
    i2 eb; eb[0] = c; eb[1] = e; PAYB[pB] = eb;
  }
}

// ---- phase 3 (combined): per-bucket finalize -> CSR entries + offsets + scales ----
__global__ __launch_bounds__(256) void finalize3(
    const int* __restrict__ KEYA, const i2* __restrict__ PAYA,
    const int* __restrict__ bbaseA, i2* __restrict__ ENTA,
    int* __restrict__ offE, int E,
    const int* __restrict__ KEYB, const i2* __restrict__ PAYB,
    const int* __restrict__ bbaseB, i2* __restrict__ ENTB,
    int* __restrict__ offN, int Nn,
    const float* __restrict__ WMf, float* __restrict__ SCE,
    float* __restrict__ ND, int nbE) {
  __shared__ int cnt[128];
  __shared__ int sc[128];
  __shared__ int cur[128];
  __shared__ float fsum[128];
  int b = blockIdx.x;
  const int* KEY; const i2* PAY; const int* bbase; i2* ENT; int* off;
  int nseg, modeB; float* outScale;
  if (b < nbE) {
    KEY = KEYA; PAY = PAYA; bbase = bbaseA; ENT = ENTA; off = offE;
    nseg = E; modeB = 0; outScale = SCE;
  } else {
    b -= nbE;
    KEY = KEYB; PAY = PAYB; bbase = bbaseB; ENT = ENTB; off = offN;
    nseg = Nn; modeB = 1; outScale = ND;
  }
  const int tid = threadIdx.x;
  const int bs = bbase[b], be = bbase[b + 1];
  const int cb = b << CW_SHIFT;
  const int cw = min(128, nseg - cb);
  if (tid < 128) { cnt[tid] = 0; fsum[tid] = 0.f; }
  __syncthreads();
  for (int k = bs + tid; k < be; k += 256) atomicAdd(&cnt[KEY[k] - cb], 1);
  __syncthreads();
  if (tid < 128) sc[tid] = cnt[tid];
  __syncthreads();
  for (int s = 1; s < 128; s <<= 1) {
    int t = (tid < 128 && tid >= s) ? sc[tid - s] : 0;
    __syncthreads();
    if (tid < 128) sc[tid] += t;
    __syncthreads();
  }
  if (tid < 128) {
    int start = bs + sc[tid] - cnt[tid];
    cur[tid] = start;
    if (tid < cw) off[cb + tid] = start;
  }
  if (tid == 0 && b == ((nseg + 127) >> CW_SHIFT) - 1) off[nseg] = be;
  __syncthreads();
  for (int k = bs + tid; k < be; k += 256) {
    int c = KEY[k] - cb;
    i2 p = PAY[k];
    int pos = atomicAdd(&cur[c], 1);
    ENT[pos] = p;
    float add = modeB ? WMf[p[0]] : __int_as_float(p[1]);
    atomicAdd(&fsum[c], add);
  }
  __syncthreads();
  if (tid < cw) {
    float s = fsum[tid] + 1e-8f;
    outScale[cb + tid] = modeB ? rsqrtf(s) : (WMf[cb + tid] / s);
  }
}

// ---- MFMA GEMM v3: LDS-staged weights + fully hoisted A loads ----
template<int KS>
__global__ __launch_bounds__(256) void gemm_mfma3(
    const void* __restrict__ Aptr, const unsigned short* __restrict__ Wt,
    const float* __restrict__ bias, unsigned short* __restrict__ out,
    int Nrows, const int* __restrict__ flags, int relu,
    const float* __restrict__ rowScale) {
  constexpr int K = KS * 32;
  constexpr int KC = K / 8;
  extern __shared__ unsigned short Bs[];
  const int tid = threadIdx.x;
  const int wv = tid >> 6, ln = tid & 63;
  const int lr = ln & 15;
  const int lk = (ln >> 4) << 3;
  const int rowBase = blockIdx.x * 128 + wv * 32;
  const int aF32 = flags ? (flags[0] ? 0 : 1) : 0;

  int ar[2];
#pragma unroll
  for (int t = 0; t < 2; ++t) {
    int r = rowBase + t * 16 + lr;
    ar[t] = (r < Nrows) ? r : (Nrows - 1);
  }

  s8b aR[2][KS];
  if (!aF32) {
#pragma unroll
    for (int t = 0; t < 2; ++t)
#pragma unroll
      for (int ks = 0; ks < KS; ++ks)
        aR[t][ks] = *reinterpret_cast<const s8b*>(
            (const unsigned short*)Aptr + (size_t)ar[t] * K + ks * 32 + lk);
  } else {
#pragma unroll
    for (int t = 0; t < 2; ++t)
#pragma unroll
      for (int ks = 0; ks < KS; ++ks) {
        const float* ap = (const float*)Aptr + (size_t)ar[t] * K + ks * 32 + lk;
        f4 u0 = *reinterpret_cast<const f4*>(ap);
        f4 u1 = *reinterpret_cast<const f4*>(ap + 4);
#pragma unroll
        for (int j = 0; j < 4; ++j) {
          aR[t][ks][j]     = (short)f2bf(u0[j]);
          aR[t][ks][4 + j] = (short)f2bf(u1[j]);
        }
      }
  }

#pragma unroll
  for (int it = 0; it < (128 * KC + 255) / 256; ++it) {
    int ch = it * 256 + tid;
    if (ch < 128 * KC) {
      int row = ch / KC, kc = (ch % KC) << 3;
      us8 v = *reinterpret_cast<const us8*>(Wt + (size_t)row * K + kc);
      int byte = ((row * K + kc) << 1) ^ ((row & 7) << 4);
      *reinterpret_cast<us8*>((char*)Bs + byte) = v;
    }
  }
  __syncthreads();

  f32x4 acc[2][8];
#pragma unroll
  for (int t = 0; t < 2; ++t)
#pragma unroll
    for (int n = 0; n < 8; ++n) acc[t][n] = (f32x4)0.f;

#pragma unroll
  for (int ks = 0; ks < KS; ++ks) {
#pragma unroll
    for (int n = 0; n < 8; ++n) {
      const int brow = n * 16 + lr;
      int byte = ((brow * K + ks * 32 + lk) << 1) ^ ((brow & 7) << 4);
      s8b b = *reinterpret_cast<const s8b*>((const char*)Bs + byte);
      acc[0][n] = __builtin_amdgcn_mfma_f32_16x16x32_bf16(aR[0][ks], b, acc[0][n], 0, 0, 0);
      acc[1][n] = __builtin_amdgcn_mfma_f32_16x16x32_bf16(aR[1][ks], b, acc[1][n], 0, 0, 0);
    }
  }

#pragma unroll
  for (int t = 0; t < 2; ++t) {
    const int orow0 = rowBase + t * 16 + ((ln >> 4) << 2);
#pragma unroll
    for (int n = 0; n < 8; ++n) {
      const int col = n * 16 + lr;
      const float bv = bias[col];
#pragma unroll
      for (int r = 0; r < 4; ++r) {
        int row = orow0 + r;
        if (row >= Nrows) continue;
        float s = acc[t][n][r] + bv;
        if (relu) s = fmaxf(s, 0.f);
        if (rowScale) s *= rowScale[row];
        out[(size_t)row * 128 + col] = f2bf(s);
      }
    }
  }
}

// ---- gather v3: 2 segments/wave, 32 lanes * us4 (8B) per row ----
__global__ __launch_bounds__(256) void gather_edge3(
    const int* __restrict__ off, const i2* __restrict__ ENT,
    const float* __restrict__ sc_e, const unsigned short* __restrict__ X,
    unsigned short* __restrict__ out, int nseg) {
  int seg = blockIdx.x * 8 + (threadIdx.x >> 5);
  if (seg >= nseg) return;
  int d = (threadIdx.x & 31) << 2;
  int k0 = off[seg], k1 = off[seg + 1];
  float a0 = 0.f, a1 = 0.f, a2 = 0.f, a3 = 0.f;
  int k = k0;
  for (; k + 4 <= k1; k += 4) {
    i2 e0 = ENT[k], e1 = ENT[k + 1], e2 = ENT[k + 2], e3 = ENT[k + 3];
    us4 v0 = *reinterpret_cast<const us4*>(X + (size_t)e0[0] * 128 + d);
    us4 v1 = *reinterpret_cast<const us4*>(X + (size_t)e1[0] * 128 + d);
    us4 v2 = *reinterpret_cast<const us4*>(X + (size_t)e2[0] * 128 + d);
    us4 v3 = *reinterpret_cast<const us4*>(X + (size_t)e3[0] * 128 + d);
    float c0 = __int_as_float(e0[1]), c1 = __int_as_float(e1[1]);
    float c2 = __int_as_float(e2[1]), c3 = __int_as_float(e3[1]);
    a0 += c0 * bf2f(v0[0]); a1 += c0 * bf2f(v0[1]); a2 += c0 * bf2f(v0[2]); a3 += c0 * bf2f(v0[3]);
    a0 += c1 * bf2f(v1[0]); a1 += c1 * bf2f(v1[1]); a2 += c1 * bf2f(v1[2]); a3 += c1 * bf2f(v1[3]);
    a0 += c2 * bf2f(v2[0]); a1 += c2 * bf2f(v2[1]); a2 += c2 * bf2f(v2[2]); a3 += c2 * bf2f(v2[3]);
    a0 += c3 * bf2f(v3[0]); a1 += c3 * bf2f(v3[1]); a2 += c3 * bf2f(v3[2]); a3 += c3 * bf2f(v3[3]);
  }
  for (; k < k1; ++k) {
    i2 e = ENT[k];
    us4 v = *reinterpret_cast<const us4*>(X + (size_t)e[0] * 128 + d);
    float c = __int_as_float(e[1]);
    a0 += c * bf2f(v[0]); a1 += c * bf2f(v[1]); a2 += c * bf2f(v[2]); a3 += c * bf2f(v[3]);
  }
  float sc = sc_e[seg];
  us4 o;
  o[0] = f2bf(sc * a0); o[1] = f2bf(sc * a1); o[2] = f2bf(sc * a2); o[3] = f2bf(sc * a3);
  *reinterpret_cast<us4*>(out + (size_t)seg * 128 + d) = o;
}

__global__ __launch_bounds__(256) void gather_node3(
    const int* __restrict__ off, const i2* __restrict__ ENT,
    const float* __restrict__ nd, const unsigned short* __restrict__ HF,
    const unsigned short* __restrict__ H, void* __restrict__ out,
    int nseg, int outF32) {
  int seg = blockIdx.x * 8 + (threadIdx.x >> 5);
  if (seg >= nseg) return;
  int d = (threadIdx.x & 31) << 2;
  int k0 = off[seg], k1 = off[seg + 1];
  float a0 = 0.f, a1 = 0.f, a2 = 0.f, a3 = 0.f;
  int k = k0;
  for (; k + 4 <= k1; k += 4) {
    i2 e0 = ENT[k], e1 = ENT[k + 1], e2 = ENT[k + 2], e3 = ENT[k + 3];
    us4 v0 = *reinterpret_cast<const us4*>(HF + (size_t)e0[0] * 128 + d);
    us4 v1 = *reinterpret_cast<const us4*>(HF + (size_t)e1[0] * 128 + d);
    us4 v2 = *reinterpret_cast<const us4*>(HF + (size_t)e2[0] * 128 + d);
    us4 v3 = *reinterpret_cast<const us4*>(HF + (size_t)e3[0] * 128 + d);
    float c0 = __int_as_float(e0[1]), c1 = __int_as_float(e1[1]);
    float c2 = __int_as_float(e2[1]), c3 = __int_as_float(e3[1]);
    a0 += c0 * bf2f(v0[0]); a1 += c0 * bf2f(v0[1]); a2 += c0 * bf2f(v0[2]); a3 += c0 * bf2f(v0[3]);
    a0 += c1 * bf2f(v1[0]); a1 += c1 * bf2f(v1[1]); a2 += c1 * bf2f(v1[2]); a3 += c1 * bf2f(v1[3]);
    a0 += c2 * bf2f(v2[0]); a1 += c2 * bf2f(v2[1]); a2 += c2 * bf2f(v2[2]); a3 += c2 * bf2f(v2[3]);
    a0 += c3 * bf2f(v3[0]); a1 += c3 * bf2f(v3[1]); a2 += c3 * bf2f(v3[2]); a3 += c3 * bf2f(v3[3]);
  }
  for (; k < k1; ++k) {
    i2 e = ENT[k];
    us4 v = *reinterpret_cast<const us4*>(HF + (size_t)e[0] * 128 + d);
    float c = __int_as_float(e[1]);
    a0 += c * bf2f(v[0]); a1 += c * bf2f(v[1]); a2 += c * bf2f(v[2]); a3 += c * bf2f(v[3]);
  }
  float s = nd[seg];
  us4 h = *reinterpret_cast<const us4*>(H + (size_t)seg * 128 + d);
  float r0 = fmaxf(bf2f(h[0]) + s * a0, 0.f);
  float r1 = fmaxf(bf2f(h[1]) + s * a1, 0.f);
  float r2 = fmaxf(bf2f(h[2]) + s * a2, 0.f);
  float r3 = fmaxf(bf2f(h[3]) + s * a3, 0.f);
  if (outF32) {
    f4 o; o[0] = r0; o[1] = r1; o[2] = r2; o[3] = r3;
    *reinterpret_cast<f4*>((float*)out + (size_t)seg * 128 + d) = o;
  } else {
    us4 o; o[0] = f2bf(r0); o[1] = f2bf(r1); o[2] = f2bf(r2); o[3] = f2bf(r3);
    *reinterpret_cast<us4*>((unsigned short*)out + (size_t)seg * 128 + d) = o;
  }
}

extern "C" void kernel_launch(void* const* d_in, const int* in_sizes, int n_in,
                              void* d_out, int out_size, void* d_ws, size_t ws_size,
                              hipStream_t stream) {
  const void* x   = d_in[0];
  const void* hei = d_in[1];
  const void* wM  = d_in[2];
  const void* ew  = d_in[3];
  const void* fcw = d_in[4];
  const void* fcb = d_in[5];
  const void* cw  = d_in[6];
  const void* cb  = d_in[7];

  const int IN_DIM = 256, D = 128;
  const int N = in_sizes[0] / IN_DIM;
  const int M = in_sizes[1] / 2;
  const int E = in_sizes[2];
  const int L = in_sizes[6] / (D * D);

  const int nbE = (E + 127) >> CW_SHIFT;
  const int nbN = (N + 127) >> CW_SHIFT;
  const int nbT = nbE + nbN;
  const int nblk = (M + CH - 1) / CH;

  float* w = (float*)d_ws;
  size_t o = 0;
  auto alloc = [&](size_t n) { float* p = w + o; o += (n + 3) & ~(size_t)3; return p; };

  // R region: XT+HF later; KEY/PAY bin arrays earlier (disjoint in time)
  float* R = alloc((size_t)(N + E) * D / 2);
  unsigned short* XT = (unsigned short*)R;
  unsigned short* HF = XT + (size_t)N * D;
  int* KEYA = (int*)R;
  i2*  PAYA = (i2*)(KEYA + M);
  int* KEYB = (int*)(PAYA + M);
  i2*  PAYB = (i2*)(KEYB + M);

  unsigned short* H  = (unsigned short*)alloc((size_t)N * D / 2);
  i2*    ENTA = (i2*)alloc((size_t)M * 2);
  i2*    ENTB = (i2*)alloc((size_t)M * 2);
  int*   cntAB = (int*)alloc((size_t)nbT * nblk);
  int*   btotAB = (int*)alloc(nbT + 2);
  int*   bbaseA = (int*)alloc(nbE + 2);
  int*   bbaseB = (int*)alloc(nbN + 2);
  float* ND   = alloc(N);
  float* SCE  = alloc(E);
  int*   offE = (int*)alloc(E + 1);
  int*   offN = (int*)alloc(N + 1);
  float* WMf  = alloc(E);
  unsigned short* FCWT = (unsigned short*)alloc((size_t)IN_DIM * D / 2);
  float* FCB  = alloc(D);
  unsigned short* CWT = (unsigned short*)alloc((size_t)L * D * D / 2);
  float* CBf  = alloc((size_t)L * D);
  int*   FLAGS = (int*)alloc(16);

  detect_kernel<<<1, 64, 0, stream>>>((const unsigned int*)x, (const unsigned int*)hei, FLAGS);

  bin_count<<<nblk, 256, 0, stream>>>(hei, M, cntAB, nbE, nbN, nblk, FLAGS);
  {
    int ntot = E + IN_DIM * D + D + L * D * D + L * D;
    cvt_params<<<(ntot + 255) / 256, 256, 0, stream>>>(wM, fcw, fcb, cw, cb,
                                                       WMf, FCWT, FCB, CWT, CBf,
                                                       E, L, FLAGS);
  }

  scanA<<<nbT, 512, 0, stream>>>(cntAB, btotAB, nblk);
  scanB<<<2, 512, 0, stream>>>(btotAB, bbaseA, bbaseB, nbE, nbN);

  binscatter<<<nblk, 256, 0, stream>>>(hei, ew, M, cntAB, bbaseA, bbaseB,
                                       KEYA, PAYA, KEYB, PAYB, nbE, nbN, nblk, FLAGS);

  finalize3<<<nbT, 256, 0, stream>>>(KEYA, PAYA, bbaseA, ENTA, offE, E,
                                     KEYB, PAYB, bbaseB, ENTB, offN, N,
                                     WMf, SCE, ND, nbE);

  // h0 = relu(x @ fc_w + fc_b)
  gemm_mfma3<8><<<(N + 127) / 128, 256, 128 * 256 * 2, stream>>>(
      x, FCWT, FCB, H, N, FLAGS, 1, nullptr);

  int segBlkE = (E + 7) / 8, segBlkN = (N + 7) / 8;
  for (int l = 0; l < L; ++l) {
    // xt' = nd[r] * (h @ conv_w[l] + conv_b[l])
    gemm_mfma3<4><<<(N + 127) / 128, 256, 128 * 128 * 2, stream>>>(
        H, CWT + (size_t)l * D * D, CBf + (size_t)l * D, XT, N,
        (const int*)nullptr, 0, ND);
    gather_edge3<<<segBlkE, 256, 0, stream>>>(offE, ENTA, SCE, XT, HF, E);
    gather_node3<<<segBlkN, 256, 0, stream>>>(
        offN, ENTB, ND, HF, H,
        (l == L - 1) ? d_out : (void*)H, N, (l == L - 1) ? 1 : 0);
  }
}